// Round 1
// baseline (2081.744 us; speedup 1.0000x reference)
//
#include <hip/hip_runtime.h>
#include <hip/hip_bf16.h>
#include <math.h>

// Shapes
#define B_  4
#define CC_ 3
#define HH_ 224
#define WW_ 224
#define PP_ 16
#define E_  768
#define NH_ 12
#define DH_ 64
#define LL_ 2
#define DFF_ 3072
#define OUT_ 1000
#define NP__ 196           // 14*14
#define S_  197            // NP_+1
#define ROWS_ (B_*S_)      // 788

__device__ __forceinline__ float gelu_f(float x) {
    float x3 = x * x * x;
    return 0.5f * x * (1.0f + tanhf(0.7978845608028654f * (x + 0.044715f * x3)));
}

// ---------------- cls token fill: h[b,0,:] = cls ----------------
__global__ __launch_bounds__(256) void cls_fill_kernel(const float* __restrict__ ct,
                                                       float* __restrict__ h) {
    int b = blockIdx.x;
    int t = threadIdx.x;
    h[(size_t)b * S_ * E_ + t]       = ct[t];
    h[(size_t)b * S_ * E_ + t + 256] = ct[t + 256];
    h[(size_t)b * S_ * E_ + t + 512] = ct[t + 512];
}

// ---------------- patch embed: gathered-A GEMM ----------------
// tok[row=(b,hp,wp), e] = sum_k patch[row,k] * conv_w[e,k] + conv_b[e] + pos_embed[pr,e]
// written into h[b, 1+pr, e]
__global__ __launch_bounds__(256) void patch_embed_kernel(const float* __restrict__ x,
                                                          const float* __restrict__ cw,
                                                          const float* __restrict__ cb,
                                                          const float* __restrict__ pe,
                                                          float* __restrict__ h) {
    __shared__ float As[16][68];
    __shared__ float Ws[16][68];
    const int tid = threadIdx.x;
    const int tx = tid & 15, ty = tid >> 4;
    const int m0 = blockIdx.y * 64, n0 = blockIdx.x * 64;
    float acc[4][4] = {};
    for (int k0 = 0; k0 < 768; k0 += 16) {
        __syncthreads();
#pragma unroll
        for (int r = 0; r < 4; ++r) {
            int idx = tid + r * 256;
            int row = idx >> 4, col = idx & 15;
            int gm = m0 + row;
            float val = 0.f;
            if (gm < 784) {
                int b  = gm / 196;
                int pr = gm - b * 196;
                int hp = pr / 14;
                int wp = pr - hp * 14;
                int k  = k0 + col;
                int c   = k >> 8;
                int rem = k & 255;
                int p   = rem >> 4;
                int q   = rem & 15;
                val = x[(((size_t)(b * 3 + c) * 224) + hp * 16 + p) * 224 + wp * 16 + q];
            }
            As[col][row] = val;
        }
#pragma unroll
        for (int r = 0; r < 4; ++r) {
            int idx = tid + r * 256;
            int cc2 = idx >> 4;   // 0..63 (e col)
            int kr  = idx & 15;
            Ws[kr][cc2] = cw[(size_t)(n0 + cc2) * 768 + (k0 + kr)];
        }
        __syncthreads();
#pragma unroll
        for (int kk = 0; kk < 16; ++kk) {
            float4 av = *(const float4*)(&As[kk][ty * 4]);
            float4 wv = *(const float4*)(&Ws[kk][tx * 4]);
            float a[4] = {av.x, av.y, av.z, av.w};
            float w[4] = {wv.x, wv.y, wv.z, wv.w};
#pragma unroll
            for (int i = 0; i < 4; ++i)
#pragma unroll
                for (int j = 0; j < 4; ++j) acc[i][j] += a[i] * w[j];
        }
    }
#pragma unroll
    for (int i = 0; i < 4; ++i) {
        int gm = m0 + ty * 4 + i;
        if (gm < 784) {
            int b  = gm / 196;
            int pr = gm - b * 196;
#pragma unroll
            for (int j = 0; j < 4; ++j) {
                int e = n0 + tx * 4 + j;
                float v = acc[i][j] + cb[e] + pe[(size_t)pr * 768 + e];
                h[((size_t)b * S_ + 1 + pr) * E_ + e] = v;
            }
        }
    }
}

// ---------------- generic GEMM: C = act(A @ W + bias) (+ residual) ----------------
// A: [M,K] row-major, W: [K,N] row-major. act: 0=none, 1=gelu
__global__ __launch_bounds__(256) void gemm_kernel(const float* __restrict__ A,
                                                   const float* __restrict__ W,
                                                   const float* __restrict__ bias,
                                                   const float* __restrict__ res,
                                                   float* __restrict__ C,
                                                   int M, int N, int K, int act) {
    __shared__ float As[16][68];
    __shared__ float Ws[16][68];
    const int tid = threadIdx.x;
    const int tx = tid & 15, ty = tid >> 4;
    const int m0 = blockIdx.y * 64, n0 = blockIdx.x * 64;
    float acc[4][4] = {};
    for (int k0 = 0; k0 < K; k0 += 16) {
        __syncthreads();
#pragma unroll
        for (int r = 0; r < 4; ++r) {
            int idx = tid + r * 256;
            int row = idx >> 4, col = idx & 15;
            int gm = m0 + row;
            As[col][row] = (gm < M) ? A[(size_t)gm * K + k0 + col] : 0.f;
        }
#pragma unroll
        for (int r = 0; r < 4; ++r) {
            int idx = tid + r * 256;
            int kr = idx >> 6;      // 0..15
            int cc = idx & 63;      // 0..63
            Ws[kr][cc] = W[(size_t)(k0 + kr) * N + n0 + cc];
        }
        __syncthreads();
#pragma unroll
        for (int kk = 0; kk < 16; ++kk) {
            float4 av = *(const float4*)(&As[kk][ty * 4]);
            float4 wv = *(const float4*)(&Ws[kk][tx * 4]);
            float a[4] = {av.x, av.y, av.z, av.w};
            float w[4] = {wv.x, wv.y, wv.z, wv.w};
#pragma unroll
            for (int i = 0; i < 4; ++i)
#pragma unroll
                for (int j = 0; j < 4; ++j) acc[i][j] += a[i] * w[j];
        }
    }
#pragma unroll
    for (int i = 0; i < 4; ++i) {
        int gm = m0 + ty * 4 + i;
        if (gm < M) {
#pragma unroll
            for (int j = 0; j < 4; ++j) {
                int gn = n0 + tx * 4 + j;
                if (gn < N) {
                    float v = acc[i][j] + bias[gn];
                    if (act == 1) v = gelu_f(v);
                    if (res) v += res[(size_t)gm * N + gn];
                    C[(size_t)gm * N + gn] = v;
                }
            }
        }
    }
}

// ---------------- LayerNorm over last dim (768) ----------------
__global__ __launch_bounds__(256) void layernorm_kernel(const float* __restrict__ x,
                                                        const float* __restrict__ w,
                                                        const float* __restrict__ b,
                                                        float* __restrict__ y) {
    int row = blockIdx.x;
    const float* xr = x + (size_t)row * E_;
    int tid = threadIdx.x;
    float v0 = xr[tid], v1 = xr[tid + 256], v2 = xr[tid + 512];
    float s  = v0 + v1 + v2;
    float sq = v0 * v0 + v1 * v1 + v2 * v2;
#pragma unroll
    for (int m = 1; m < 64; m <<= 1) {
        s  += __shfl_xor(s, m, 64);
        sq += __shfl_xor(sq, m, 64);
    }
    __shared__ float ss[4], sqs[4];
    int wave = tid >> 6, lane = tid & 63;
    if (lane == 0) { ss[wave] = s; sqs[wave] = sq; }
    __syncthreads();
    s  = ss[0] + ss[1] + ss[2] + ss[3];
    sq = sqs[0] + sqs[1] + sqs[2] + sqs[3];
    float mu   = s * (1.0f / 768.0f);
    float var  = sq * (1.0f / 768.0f) - mu * mu;
    float rstd = rsqrtf(var + 1e-5f);
    float* yr = y + (size_t)row * E_;
    yr[tid]       = (v0 - mu) * rstd * w[tid]       + b[tid];
    yr[tid + 256] = (v1 - mu) * rstd * w[tid + 256] + b[tid + 256];
    yr[tid + 512] = (v2 - mu) * rstd * w[tid + 512] + b[tid + 512];
}

// ---------------- Tversky attention core ----------------
// qkv: [B, S, 3E]; o: [B, S, E]. One wave per (b, head, i); lane = d (DH=64).
__global__ __launch_bounds__(256) void tversky_attn_kernel(const float* __restrict__ qkv,
                                                           float* __restrict__ o) {
    __shared__ float p_s[4][200];
    const int wave = threadIdx.x >> 6;
    const int lane = threadIdx.x & 63;
    int i = blockIdx.x * 4 + wave;
    const bool valid = (i < S_);
    if (i > S_ - 1) i = S_ - 1;
    const int hh = blockIdx.y, bb = blockIdx.z;

    const float* qrow = qkv + ((size_t)(bb * S_ + i)) * (3 * E_) + hh * DH_;
    float qp = fmaxf(qrow[lane], 0.f);
    float qs = qp;
#pragma unroll
    for (int m = 1; m < 64; m <<= 1) qs += __shfl_xor(qs, m, 64);

    const float* kbase = qkv + (size_t)bb * S_ * (3 * E_) + E_ + hh * DH_;
    for (int j = 0; j < S_; ++j) {
        float kv = fmaxf(kbase[(size_t)j * (3 * E_) + lane], 0.f);
        float l1 = fabsf(qp - kv);
        float ks = kv;
#pragma unroll
        for (int m = 1; m < 64; m <<= 1) {
            l1 += __shfl_xor(l1, m, 64);
            ks += __shfl_xor(ks, m, 64);
        }
        float inter = 0.5f * (qs + ks - l1);
        float amb   = 0.5f * (l1 + qs - ks);
        float bma   = 0.5f * (l1 - qs + ks);
        float sc = (1.0f * inter) / (inter + 0.5f * amb + 0.5f * bma + 1e-8f);
        if (lane == 0) p_s[wave][j] = sc;
    }

    // softmax over j within the wave
    float vmax = -3.4e38f;
    for (int j = lane; j < S_; j += 64) vmax = fmaxf(vmax, p_s[wave][j]);
#pragma unroll
    for (int m = 1; m < 64; m <<= 1) vmax = fmaxf(vmax, __shfl_xor(vmax, m, 64));
    float sum = 0.f;
    for (int j = lane; j < S_; j += 64) {
        float e = expf(p_s[wave][j] - vmax);
        p_s[wave][j] = e;
        sum += e;
    }
#pragma unroll
    for (int m = 1; m < 64; m <<= 1) sum += __shfl_xor(sum, m, 64);
    float inv = 1.f / sum;

    const float* vbase = qkv + (size_t)bb * S_ * (3 * E_) + 2 * E_ + hh * DH_;
    float acc = 0.f;
    for (int j = 0; j < S_; ++j) acc += p_s[wave][j] * vbase[(size_t)j * (3 * E_) + lane];
    if (valid) o[((size_t)(bb * S_) + i) * E_ + hh * DH_ + lane] = acc * inv;
}

// ---------------- head: out[b,n] = ln[b,0,:] @ head_w + head_b ----------------
__global__ __launch_bounds__(256) void head_kernel(const float* __restrict__ ln,
                                                   const float* __restrict__ hw,
                                                   const float* __restrict__ hb,
                                                   float* __restrict__ out) {
    int b = blockIdx.y;
    int n = blockIdx.x * 256 + threadIdx.x;
    __shared__ float xr[E_];
    for (int e = threadIdx.x; e < E_; e += 256) xr[e] = ln[((size_t)b * S_) * E_ + e];
    __syncthreads();
    if (n < OUT_) {
        float acc = hb[n];
        for (int e = 0; e < E_; ++e) acc += xr[e] * hw[(size_t)e * OUT_ + n];
        out[(size_t)b * OUT_ + n] = acc;
    }
}

extern "C" void kernel_launch(void* const* d_in, const int* in_sizes, int n_in,
                              void* d_out, int out_size, void* d_ws, size_t ws_size,
                              hipStream_t stream) {
    const float* x        = (const float*)d_in[0];
    const float* conv_w   = (const float*)d_in[1];
    const float* conv_b   = (const float*)d_in[2];
    const float* pos_e    = (const float*)d_in[3];
    const float* cls_t    = (const float*)d_in[4];
    const float* ln1_w    = (const float*)d_in[5];
    const float* ln1_b    = (const float*)d_in[6];
    const float* attn_w   = (const float*)d_in[7];
    const float* attn_b   = (const float*)d_in[8];
    const float* proj_w   = (const float*)d_in[9];
    const float* proj_b   = (const float*)d_in[10];
    const float* ln2_w    = (const float*)d_in[11];
    const float* ln2_b    = (const float*)d_in[12];
    const float* fc1_w    = (const float*)d_in[13];
    const float* fc1_b    = (const float*)d_in[14];
    const float* fc2_w    = (const float*)d_in[15];
    const float* fc2_b    = (const float*)d_in[16];
    const float* lnf_w    = (const float*)d_in[17];
    const float* lnf_b    = (const float*)d_in[18];
    const float* head_w   = (const float*)d_in[19];
    const float* head_b   = (const float*)d_in[20];
    float* out = (float*)d_out;

    float* ws = (float*)d_ws;
    float* h    = ws;                              // 788*768
    float* lnb  = h + (size_t)ROWS_ * E_;          // 788*768
    float* qkv  = lnb + (size_t)ROWS_ * E_;        // 788*2304
    float* ao   = qkv + (size_t)ROWS_ * 3 * E_;    // 788*768
    float* hid  = ao + (size_t)ROWS_ * E_;         // 788*3072

    // patch embed + cls
    {
        dim3 grid(768 / 64, (784 + 63) / 64);
        patch_embed_kernel<<<grid, 256, 0, stream>>>(x, conv_w, conv_b, pos_e, h);
        cls_fill_kernel<<<B_, 256, 0, stream>>>(cls_t, h);
    }

    for (int l = 0; l < LL_; ++l) {
        // LN1
        layernorm_kernel<<<ROWS_, 256, 0, stream>>>(h, ln1_w + l * E_, ln1_b + l * E_, lnb);
        // QKV
        {
            dim3 grid((3 * E_) / 64, (ROWS_ + 63) / 64);
            gemm_kernel<<<grid, 256, 0, stream>>>(lnb, attn_w + (size_t)l * E_ * 3 * E_,
                                                  attn_b + (size_t)l * 3 * E_, nullptr, qkv,
                                                  ROWS_, 3 * E_, E_, 0);
        }
        // attention
        {
            dim3 grid((S_ + 3) / 4, NH_, B_);
            tversky_attn_kernel<<<grid, 256, 0, stream>>>(qkv, ao);
        }
        // proj + residual into h
        {
            dim3 grid(E_ / 64, (ROWS_ + 63) / 64);
            gemm_kernel<<<grid, 256, 0, stream>>>(ao, proj_w + (size_t)l * E_ * E_,
                                                  proj_b + (size_t)l * E_, h, h,
                                                  ROWS_, E_, E_, 0);
        }
        // LN2
        layernorm_kernel<<<ROWS_, 256, 0, stream>>>(h, ln2_w + l * E_, ln2_b + l * E_, lnb);
        // fc1 + gelu
        {
            dim3 grid(DFF_ / 64, (ROWS_ + 63) / 64);
            gemm_kernel<<<grid, 256, 0, stream>>>(lnb, fc1_w + (size_t)l * E_ * DFF_,
                                                  fc1_b + (size_t)l * DFF_, nullptr, hid,
                                                  ROWS_, DFF_, E_, 1);
        }
        // fc2 + residual into h
        {
            dim3 grid(E_ / 64, (ROWS_ + 63) / 64);
            gemm_kernel<<<grid, 256, 0, stream>>>(hid, fc2_w + (size_t)l * DFF_ * E_,
                                                  fc2_b + (size_t)l * E_, h, h,
                                                  ROWS_, E_, DFF_, 0);
        }
    }

    // final LN + head
    layernorm_kernel<<<ROWS_, 256, 0, stream>>>(h, lnf_w, lnf_b, lnb);
    {
        dim3 grid((OUT_ + 255) / 256, B_);
        head_kernel<<<grid, 256, 0, stream>>>(lnb, head_w, head_b, out);
    }
}

// Round 2
// 1636.350 us; speedup vs baseline: 1.2722x; 1.2722x over previous
//
#include <hip/hip_runtime.h>
#include <hip/hip_bf16.h>
#include <math.h>

// Shapes
#define B_  4
#define CC_ 3
#define HH_ 224
#define WW_ 224
#define PP_ 16
#define E_  768
#define NH_ 12
#define DH_ 64
#define LL_ 2
#define DFF_ 3072
#define OUT_ 1000
#define NP__ 196           // 14*14
#define S_  197            // NP_+1
#define ROWS_ (B_*S_)      // 788

__device__ __forceinline__ float gelu_f(float x) {
    float x3 = x * x * x;
    return 0.5f * x * (1.0f + tanhf(0.7978845608028654f * (x + 0.044715f * x3)));
}

// ---------------- cls token fill: h[b,0,:] = cls ----------------
__global__ __launch_bounds__(256) void cls_fill_kernel(const float* __restrict__ ct,
                                                       float* __restrict__ h) {
    int b = blockIdx.x;
    int t = threadIdx.x;
    h[(size_t)b * S_ * E_ + t]       = ct[t];
    h[(size_t)b * S_ * E_ + t + 256] = ct[t + 256];
    h[(size_t)b * S_ * E_ + t + 512] = ct[t + 512];
}

// ---------------- patch embed: gathered-A GEMM ----------------
__global__ __launch_bounds__(256) void patch_embed_kernel(const float* __restrict__ x,
                                                          const float* __restrict__ cw,
                                                          const float* __restrict__ cb,
                                                          const float* __restrict__ pe,
                                                          float* __restrict__ h) {
    __shared__ float As[16][68];
    __shared__ float Ws[16][68];
    const int tid = threadIdx.x;
    const int tx = tid & 15, ty = tid >> 4;
    const int m0 = blockIdx.y * 64, n0 = blockIdx.x * 64;
    float acc[4][4] = {};
    for (int k0 = 0; k0 < 768; k0 += 16) {
        __syncthreads();
#pragma unroll
        for (int r = 0; r < 4; ++r) {
            int idx = tid + r * 256;
            int row = idx >> 4, col = idx & 15;
            int gm = m0 + row;
            float val = 0.f;
            if (gm < 784) {
                int b  = gm / 196;
                int pr = gm - b * 196;
                int hp = pr / 14;
                int wp = pr - hp * 14;
                int k  = k0 + col;
                int c   = k >> 8;
                int rem = k & 255;
                int p   = rem >> 4;
                int q   = rem & 15;
                val = x[(((size_t)(b * 3 + c) * 224) + hp * 16 + p) * 224 + wp * 16 + q];
            }
            As[col][row] = val;
        }
#pragma unroll
        for (int r = 0; r < 4; ++r) {
            int idx = tid + r * 256;
            int cc2 = idx >> 4;   // 0..63 (e col)
            int kr  = idx & 15;
            Ws[kr][cc2] = cw[(size_t)(n0 + cc2) * 768 + (k0 + kr)];
        }
        __syncthreads();
#pragma unroll
        for (int kk = 0; kk < 16; ++kk) {
            float4 av = *(const float4*)(&As[kk][ty * 4]);
            float4 wv = *(const float4*)(&Ws[kk][tx * 4]);
            float a[4] = {av.x, av.y, av.z, av.w};
            float w[4] = {wv.x, wv.y, wv.z, wv.w};
#pragma unroll
            for (int i = 0; i < 4; ++i)
#pragma unroll
                for (int j = 0; j < 4; ++j) acc[i][j] += a[i] * w[j];
        }
    }
#pragma unroll
    for (int i = 0; i < 4; ++i) {
        int gm = m0 + ty * 4 + i;
        if (gm < 784) {
            int b  = gm / 196;
            int pr = gm - b * 196;
#pragma unroll
            for (int j = 0; j < 4; ++j) {
                int e = n0 + tx * 4 + j;
                float v = acc[i][j] + cb[e] + pe[(size_t)pr * 768 + e];
                h[((size_t)b * S_ + 1 + pr) * E_ + e] = v;
            }
        }
    }
}

// ---------------- generic GEMM: C = act(A @ W + bias) (+ residual) ----------------
__global__ __launch_bounds__(256) void gemm_kernel(const float* __restrict__ A,
                                                   const float* __restrict__ W,
                                                   const float* __restrict__ bias,
                                                   const float* __restrict__ res,
                                                   float* __restrict__ C,
                                                   int M, int N, int K, int act) {
    __shared__ float As[16][68];
    __shared__ float Ws[16][68];
    const int tid = threadIdx.x;
    const int tx = tid & 15, ty = tid >> 4;
    const int m0 = blockIdx.y * 64, n0 = blockIdx.x * 64;
    float acc[4][4] = {};
    for (int k0 = 0; k0 < K; k0 += 16) {
        __syncthreads();
#pragma unroll
        for (int r = 0; r < 4; ++r) {
            int idx = tid + r * 256;
            int row = idx >> 4, col = idx & 15;
            int gm = m0 + row;
            As[col][row] = (gm < M) ? A[(size_t)gm * K + k0 + col] : 0.f;
        }
#pragma unroll
        for (int r = 0; r < 4; ++r) {
            int idx = tid + r * 256;
            int kr = idx >> 6;      // 0..15
            int cc = idx & 63;      // 0..63
            Ws[kr][cc] = W[(size_t)(k0 + kr) * N + n0 + cc];
        }
        __syncthreads();
#pragma unroll
        for (int kk = 0; kk < 16; ++kk) {
            float4 av = *(const float4*)(&As[kk][ty * 4]);
            float4 wv = *(const float4*)(&Ws[kk][tx * 4]);
            float a[4] = {av.x, av.y, av.z, av.w};
            float w[4] = {wv.x, wv.y, wv.z, wv.w};
#pragma unroll
            for (int i = 0; i < 4; ++i)
#pragma unroll
                for (int j = 0; j < 4; ++j) acc[i][j] += a[i] * w[j];
        }
    }
#pragma unroll
    for (int i = 0; i < 4; ++i) {
        int gm = m0 + ty * 4 + i;
        if (gm < M) {
#pragma unroll
            for (int j = 0; j < 4; ++j) {
                int gn = n0 + tx * 4 + j;
                if (gn < N) {
                    float v = acc[i][j] + bias[gn];
                    if (act == 1) v = gelu_f(v);
                    if (res) v += res[(size_t)gm * N + gn];
                    C[(size_t)gm * N + gn] = v;
                }
            }
        }
    }
}

// ---------------- LayerNorm over last dim (768) ----------------
__global__ __launch_bounds__(256) void layernorm_kernel(const float* __restrict__ x,
                                                        const float* __restrict__ w,
                                                        const float* __restrict__ b,
                                                        float* __restrict__ y) {
    int row = blockIdx.x;
    const float* xr = x + (size_t)row * E_;
    int tid = threadIdx.x;
    float v0 = xr[tid], v1 = xr[tid + 256], v2 = xr[tid + 512];
    float s  = v0 + v1 + v2;
    float sq = v0 * v0 + v1 * v1 + v2 * v2;
#pragma unroll
    for (int m = 1; m < 64; m <<= 1) {
        s  += __shfl_xor(s, m, 64);
        sq += __shfl_xor(sq, m, 64);
    }
    __shared__ float ss[4], sqs[4];
    int wave = tid >> 6, lane = tid & 63;
    if (lane == 0) { ss[wave] = s; sqs[wave] = sq; }
    __syncthreads();
    s  = ss[0] + ss[1] + ss[2] + ss[3];
    sq = sqs[0] + sqs[1] + sqs[2] + sqs[3];
    float mu   = s * (1.0f / 768.0f);
    float var  = sq * (1.0f / 768.0f) - mu * mu;
    float rstd = rsqrtf(var + 1e-5f);
    float* yr = y + (size_t)row * E_;
    yr[tid]       = (v0 - mu) * rstd * w[tid]       + b[tid];
    yr[tid + 256] = (v1 - mu) * rstd * w[tid + 256] + b[tid + 256];
    yr[tid + 512] = (v2 - mu) * rstd * w[tid + 512] + b[tid + 512];
}

// ---------------- Tversky attention core (lane = j layout) ----------------
// score(i,j) = (qs+ks-l1)/(qs+ks+2eps)  [exact algebraic reduction for a=b=0.5,g=1]
// Block: one (b,h) head, chunk of 40 q-rows. K^T staged relu'd in LDS, pitch 201
// (201 mod 32 = 9, coprime with 32 -> conflict-free rows AND columns).
#define KT_P 201
#define CH_ROWS 40
__global__ __launch_bounds__(256) void tversky_attn_kernel(const float* __restrict__ qkv,
                                                           float* __restrict__ o) {
    __shared__ float kT[64 * KT_P];          // 51456 B
    __shared__ float ks_lds[200];
    __shared__ __align__(16) float q_lds[4][64];
    __shared__ __align__(16) float p_lds[4][200];

    const int tid  = threadIdx.x;
    const int wave = tid >> 6;
    const int lane = tid & 63;
    const int ch = blockIdx.x, hh = blockIdx.y, bb = blockIdx.z;
    const float* kbase = qkv + (size_t)bb * S_ * (3 * E_) + E_ + hh * DH_;

    // ---- stage relu(K)^T and ks ----
    // idx layout: 64 consecutive tids = one j row => wave butterfly gives ks[j]
    for (int c = 0; c < (S_ * 64 + 255) / 256; ++c) {
        int idx = c * 256 + tid;
        int j = idx >> 6, d = idx & 63;
        bool valid = (j < S_);
        float val = 0.f;
        if (valid) {
            val = fmaxf(kbase[(size_t)j * (3 * E_) + d], 0.f);
            kT[d * KT_P + j] = val;
        }
        float s = val;
#pragma unroll
        for (int m = 1; m < 64; m <<= 1) s += __shfl_xor(s, m, 64);
        if (valid && lane == 0) ks_lds[j] = s;
    }
    __syncthreads();

    const int j0 = lane, j1 = lane + 64, j2 = lane + 128;
    const int j3 = (lane < 5) ? (lane + 192) : lane;   // clamped (masked later)

    const int i_begin = ch * CH_ROWS;
    const int i_end   = min(S_, i_begin + CH_ROWS);
    for (int i = i_begin + wave; i < i_end; i += 4) {
        // q row -> LDS + qs
        const float* qrow = qkv + ((size_t)(bb * S_ + i)) * (3 * E_) + hh * DH_;
        float qp = fmaxf(qrow[lane], 0.f);
        float qs = qp;
#pragma unroll
        for (int m = 1; m < 64; m <<= 1) qs += __shfl_xor(qs, m, 64);
        q_lds[wave][lane] = qp;

        // l1 over 4 j-strips; lane = j within strip
        float l0 = 0.f, l1a = 0.f, l2a = 0.f, l3a = 0.f;
        const float* qw = &q_lds[wave][0];
#pragma unroll 8
        for (int d = 0; d < 64; ++d) {
            float qv = qw[d];
            const float* kr = &kT[d * KT_P];
            l0  += fabsf(qv - kr[j0]);
            l1a += fabsf(qv - kr[j1]);
            l2a += fabsf(qv - kr[j2]);
            l3a += fabsf(qv - kr[j3]);
        }
        float s0 = qs + ks_lds[j0];
        float s1 = qs + ks_lds[j1];
        float s2 = qs + ks_lds[j2];
        float s3 = qs + ks_lds[j3];
        float sc0 = (s0 - l0)  / (s0 + 2e-8f);
        float sc1 = (s1 - l1a) / (s1 + 2e-8f);
        float sc2 = (s2 - l2a) / (s2 + 2e-8f);
        float sc3 = (lane < 5) ? (s3 - l3a) / (s3 + 2e-8f) : -1e30f;

        // softmax across j (butterfly over lanes x 4 strips)
        float vmax = fmaxf(fmaxf(sc0, sc1), fmaxf(sc2, sc3));
#pragma unroll
        for (int m = 1; m < 64; m <<= 1) vmax = fmaxf(vmax, __shfl_xor(vmax, m, 64));
        float e0 = expf(sc0 - vmax);
        float e1 = expf(sc1 - vmax);
        float e2 = expf(sc2 - vmax);
        float e3 = (lane < 5) ? expf(sc3 - vmax) : 0.f;
        float sum = e0 + e1 + e2 + e3;
#pragma unroll
        for (int m = 1; m < 64; m <<= 1) sum += __shfl_xor(sum, m, 64);
        float inv = 1.f / sum;
        p_lds[wave][j0] = e0 * inv;
        p_lds[wave][j1] = e1 * inv;
        p_lds[wave][j2] = e2 * inv;
        if (lane < 5) p_lds[wave][lane + 192] = e3 * inv;

        // PV: lane = d, p broadcast from LDS (float4), V coalesced from global
        const float* vbase = qkv + (size_t)bb * S_ * (3 * E_) + 2 * E_ + hh * DH_ + lane;
        float acc = 0.f;
#pragma unroll 4
        for (int j4 = 0; j4 < 196; j4 += 4) {
            float4 p4 = *(const float4*)&p_lds[wave][j4];
            acc += p4.x * vbase[(size_t)(j4 + 0) * (3 * E_)];
            acc += p4.y * vbase[(size_t)(j4 + 1) * (3 * E_)];
            acc += p4.z * vbase[(size_t)(j4 + 2) * (3 * E_)];
            acc += p4.w * vbase[(size_t)(j4 + 3) * (3 * E_)];
        }
        acc += p_lds[wave][196] * vbase[(size_t)196 * (3 * E_)];
        o[((size_t)(bb * S_) + i) * E_ + hh * DH_ + lane] = acc;
    }
}

// ---------------- head ----------------
__global__ __launch_bounds__(256) void head_kernel(const float* __restrict__ ln,
                                                   const float* __restrict__ hw,
                                                   const float* __restrict__ hb,
                                                   float* __restrict__ out) {
    int b = blockIdx.y;
    int n = blockIdx.x * 256 + threadIdx.x;
    __shared__ float xr[E_];
    for (int e = threadIdx.x; e < E_; e += 256) xr[e] = ln[((size_t)b * S_) * E_ + e];
    __syncthreads();
    if (n < OUT_) {
        float acc = hb[n];
        for (int e = 0; e < E_; ++e) acc += xr[e] * hw[(size_t)e * OUT_ + n];
        out[(size_t)b * OUT_ + n] = acc;
    }
}

extern "C" void kernel_launch(void* const* d_in, const int* in_sizes, int n_in,
                              void* d_out, int out_size, void* d_ws, size_t ws_size,
                              hipStream_t stream) {
    const float* x        = (const float*)d_in[0];
    const float* conv_w   = (const float*)d_in[1];
    const float* conv_b   = (const float*)d_in[2];
    const float* pos_e    = (const float*)d_in[3];
    const float* cls_t    = (const float*)d_in[4];
    const float* ln1_w    = (const float*)d_in[5];
    const float* ln1_b    = (const float*)d_in[6];
    const float* attn_w   = (const float*)d_in[7];
    const float* attn_b   = (const float*)d_in[8];
    const float* proj_w   = (const float*)d_in[9];
    const float* proj_b   = (const float*)d_in[10];
    const float* ln2_w    = (const float*)d_in[11];
    const float* ln2_b    = (const float*)d_in[12];
    const float* fc1_w    = (const float*)d_in[13];
    const float* fc1_b    = (const float*)d_in[14];
    const float* fc2_w    = (const float*)d_in[15];
    const float* fc2_b    = (const float*)d_in[16];
    const float* lnf_w    = (const float*)d_in[17];
    const float* lnf_b    = (const float*)d_in[18];
    const float* head_w   = (const float*)d_in[19];
    const float* head_b   = (const float*)d_in[20];
    float* out = (float*)d_out;

    float* ws = (float*)d_ws;
    float* h    = ws;                              // 788*768
    float* lnb  = h + (size_t)ROWS_ * E_;          // 788*768
    float* qkv  = lnb + (size_t)ROWS_ * E_;        // 788*2304
    float* ao   = qkv + (size_t)ROWS_ * 3 * E_;    // 788*768
    float* hid  = ao + (size_t)ROWS_ * E_;         // 788*3072

    // patch embed + cls
    {
        dim3 grid(768 / 64, (784 + 63) / 64);
        patch_embed_kernel<<<grid, 256, 0, stream>>>(x, conv_w, conv_b, pos_e, h);
        cls_fill_kernel<<<B_, 256, 0, stream>>>(cls_t, h);
    }

    for (int l = 0; l < LL_; ++l) {
        layernorm_kernel<<<ROWS_, 256, 0, stream>>>(h, ln1_w + l * E_, ln1_b + l * E_, lnb);
        {
            dim3 grid((3 * E_) / 64, (ROWS_ + 63) / 64);
            gemm_kernel<<<grid, 256, 0, stream>>>(lnb, attn_w + (size_t)l * E_ * 3 * E_,
                                                  attn_b + (size_t)l * 3 * E_, nullptr, qkv,
                                                  ROWS_, 3 * E_, E_, 0);
        }
        {
            dim3 grid((S_ + CH_ROWS - 1) / CH_ROWS, NH_, B_);   // 5 x 12 x 4 = 240 blocks
            tversky_attn_kernel<<<grid, 256, 0, stream>>>(qkv, ao);
        }
        {
            dim3 grid(E_ / 64, (ROWS_ + 63) / 64);
            gemm_kernel<<<grid, 256, 0, stream>>>(ao, proj_w + (size_t)l * E_ * E_,
                                                  proj_b + (size_t)l * E_, h, h,
                                                  ROWS_, E_, E_, 0);
        }
        layernorm_kernel<<<ROWS_, 256, 0, stream>>>(h, ln2_w + l * E_, ln2_b + l * E_, lnb);
        {
            dim3 grid(DFF_ / 64, (ROWS_ + 63) / 64);
            gemm_kernel<<<grid, 256, 0, stream>>>(lnb, fc1_w + (size_t)l * E_ * DFF_,
                                                  fc1_b + (size_t)l * DFF_, nullptr, hid,
                                                  ROWS_, DFF_, E_, 1);
        }
        {
            dim3 grid(E_ / 64, (ROWS_ + 63) / 64);
            gemm_kernel<<<grid, 256, 0, stream>>>(hid, fc2_w + (size_t)l * DFF_ * E_,
                                                  fc2_b + (size_t)l * E_, h, h,
                                                  ROWS_, E_, DFF_, 0);
        }
    }

    layernorm_kernel<<<ROWS_, 256, 0, stream>>>(h, lnf_w, lnf_b, lnb);
    {
        dim3 grid((OUT_ + 255) / 256, B_);
        head_kernel<<<grid, 256, 0, stream>>>(lnb, head_w, head_b, out);
    }
}

// Round 3
// 751.285 us; speedup vs baseline: 2.7709x; 2.1781x over previous
//
#include <hip/hip_runtime.h>
#include <hip/hip_bf16.h>
#include <math.h>

// Shapes
#define B_  4
#define E_  768
#define NH_ 12
#define DH_ 64
#define LL_ 2
#define DFF_ 3072
#define OUT_ 1000
#define S_  197
#define ROWS_ 788          // B_*S_

typedef __bf16 bf16x8_t __attribute__((ext_vector_type(8)));
typedef float f32x4_t __attribute__((ext_vector_type(4)));

__device__ __forceinline__ float gelu_f(float x) {
    float x3 = x * x * x;
    return 0.5f * x * (1.0f + tanhf(0.7978845608028654f * (x + 0.044715f * x3)));
}

// ---------------- im2col to bf16: aim[row=(b,hp,wp)][k=(c,p,q)] ----------------
__global__ __launch_bounds__(256) void im2col_kernel(const float* __restrict__ x,
                                                     __hip_bfloat16* __restrict__ aim) {
    int id = blockIdx.x * 256 + threadIdx.x;        // 784*768 exact
    int row = id / 768, k = id - row * 768;
    int b = row / 196, pr = row - b * 196;
    int hp = pr / 14, wp = pr - hp * 14;
    int c = k >> 8, rem = k & 255, p = rem >> 4, q = rem & 15;
    aim[id] = __float2bfloat16(x[(((size_t)(b * 3 + c) * 224) + hp * 16 + p) * 224 + wp * 16 + q]);
}

// ---------------- flat fp32 -> bf16 convert ----------------
__global__ __launch_bounds__(256) void cvt_bf16_kernel(const float* __restrict__ in,
                                                       __hip_bfloat16* __restrict__ out, int n) {
    int i = blockIdx.x * 256 + threadIdx.x;
    if (i < n) out[i] = __float2bfloat16(in[i]);
}

// ---------------- tiled transpose + convert: in[K,N] fp32 -> out[N,K] bf16 ----------------
__global__ __launch_bounds__(256) void transpose_bf16_kernel(const float* __restrict__ in,
                                                             __hip_bfloat16* __restrict__ out,
                                                             int K, int N) {
    __shared__ __hip_bfloat16 t[32][33];
    int kb = blockIdx.y * 32, nb = blockIdx.x * 32;
    int tx = threadIdx.x & 31, ty = threadIdx.x >> 5;   // ty 0..7
#pragma unroll
    for (int r = 0; r < 32; r += 8)
        t[ty + r][tx] = __float2bfloat16(in[(size_t)(kb + ty + r) * N + nb + tx]);
    __syncthreads();
#pragma unroll
    for (int r = 0; r < 32; r += 8)
        out[(size_t)(nb + ty + r) * K + kb + tx] = t[tx][ty + r];
}

// ---------------- MFMA GEMM: C = act(A @ WT^T + bias) (+res) ----------------
// A: [M,K] bf16 (K-major). WT: [N,K] bf16 (K-major). Output fp32 (Cf) or bf16 (Cb).
#define BK 64
#define AP 72    // LDS pitch (bf16 units); 72*2=144B -> 2-way max on frag reads
__global__ __launch_bounds__(256) void gemm_mfma_kernel(const __hip_bfloat16* __restrict__ A,
                                                        const __hip_bfloat16* __restrict__ WT,
                                                        const float* __restrict__ bias,
                                                        const float* __restrict__ res,
                                                        float* __restrict__ Cf,
                                                        __hip_bfloat16* __restrict__ Cb,
                                                        int M, int N, int K, int act) {
    __shared__ __align__(16) ushort Asb[64 * AP];
    __shared__ __align__(16) ushort Bsb[64 * AP];
    const int tid = threadIdx.x;
    const int wave = tid >> 6, lane = tid & 63;
    const int quad = lane >> 4, l15 = lane & 15;
    const int wm = wave >> 1, wn = wave & 1;
    const int m0 = blockIdx.y * 64, n0 = blockIdx.x * 64;

    f32x4_t acc[2][2] = {};

    const int c0r = tid >> 3,         c0o = (tid & 7) * 8;        // chunk tid
    const int c1r = (tid + 256) >> 3, c1o = c0o;                  // chunk tid+256

    for (int k0 = 0; k0 < K; k0 += BK) {
        __syncthreads();
        // stage A (64x64 bf16), zero-fill beyond M
        {
            uint4 v = make_uint4(0, 0, 0, 0);
            int gm = m0 + c0r;
            if (gm < M) v = *(const uint4*)&A[(size_t)gm * K + k0 + c0o];
            *(uint4*)&Asb[c0r * AP + c0o] = v;
            v = make_uint4(0, 0, 0, 0);
            gm = m0 + c1r;
            if (gm < M) v = *(const uint4*)&A[(size_t)gm * K + k0 + c1o];
            *(uint4*)&Asb[c1r * AP + c1o] = v;
        }
        // stage B rows = n index (grid exact in N)
        {
            uint4 v = *(const uint4*)&WT[(size_t)(n0 + c0r) * K + k0 + c0o];
            *(uint4*)&Bsb[c0r * AP + c0o] = v;
            v = *(const uint4*)&WT[(size_t)(n0 + c1r) * K + k0 + c1o];
            *(uint4*)&Bsb[c1r * AP + c1o] = v;
        }
        __syncthreads();
#pragma unroll
        for (int ks = 0; ks < BK; ks += 32) {
            bf16x8_t a0 = *(const bf16x8_t*)&Asb[(32 * wm + l15) * AP + ks + 8 * quad];
            bf16x8_t a1 = *(const bf16x8_t*)&Asb[(32 * wm + 16 + l15) * AP + ks + 8 * quad];
            bf16x8_t b0 = *(const bf16x8_t*)&Bsb[(32 * wn + l15) * AP + ks + 8 * quad];
            bf16x8_t b1 = *(const bf16x8_t*)&Bsb[(32 * wn + 16 + l15) * AP + ks + 8 * quad];
            acc[0][0] = __builtin_amdgcn_mfma_f32_16x16x32_bf16(a0, b0, acc[0][0], 0, 0, 0);
            acc[0][1] = __builtin_amdgcn_mfma_f32_16x16x32_bf16(a0, b1, acc[0][1], 0, 0, 0);
            acc[1][0] = __builtin_amdgcn_mfma_f32_16x16x32_bf16(a1, b0, acc[1][0], 0, 0, 0);
            acc[1][1] = __builtin_amdgcn_mfma_f32_16x16x32_bf16(a1, b1, acc[1][1], 0, 0, 0);
        }
    }

#pragma unroll
    for (int mi = 0; mi < 2; ++mi)
#pragma unroll
        for (int ni = 0; ni < 2; ++ni) {
            int gn = n0 + 32 * wn + 16 * ni + l15;
#pragma unroll
            for (int r = 0; r < 4; ++r) {
                int gm = m0 + 32 * wm + 16 * mi + quad * 4 + r;
                if (gm < M) {
                    float v = acc[mi][ni][r] + bias[gn];
                    if (act == 1) v = gelu_f(v);
                    if (res) v += res[(size_t)gm * N + gn];
                    if (Cf) Cf[(size_t)gm * N + gn] = v;
                    else    Cb[(size_t)gm * N + gn] = __float2bfloat16(v);
                }
            }
        }
}

// ---------------- patch-embed finish: h[b,1+pr,:] = tmp[row,:] + pe[pr,:] ----------------
__global__ __launch_bounds__(256) void embed_finish_kernel(const float* __restrict__ tmp,
                                                           const float* __restrict__ pe,
                                                           float* __restrict__ h) {
    int row = blockIdx.x;                  // 0..783
    int b = row / 196, pr = row - b * 196;
    for (int e = threadIdx.x; e < E_; e += 256)
        h[((size_t)(b * S_ + 1 + pr)) * E_ + e] = tmp[(size_t)row * E_ + e] + pe[(size_t)pr * E_ + e];
}

__global__ __launch_bounds__(256) void cls_fill_kernel(const float* __restrict__ ct,
                                                       float* __restrict__ h) {
    int b = blockIdx.x;
    int t = threadIdx.x;
    h[(size_t)b * S_ * E_ + t]       = ct[t];
    h[(size_t)b * S_ * E_ + t + 256] = ct[t + 256];
    h[(size_t)b * S_ * E_ + t + 512] = ct[t + 512];
}

// ---------------- LayerNorm (fp32 in, bf16 out) ----------------
__global__ __launch_bounds__(256) void layernorm_kernel(const float* __restrict__ x,
                                                        const float* __restrict__ w,
                                                        const float* __restrict__ b,
                                                        __hip_bfloat16* __restrict__ y) {
    int row = blockIdx.x;
    const float* xr = x + (size_t)row * E_;
    int tid = threadIdx.x;
    float v0 = xr[tid], v1 = xr[tid + 256], v2 = xr[tid + 512];
    float s  = v0 + v1 + v2;
    float sq = v0 * v0 + v1 * v1 + v2 * v2;
#pragma unroll
    for (int m = 1; m < 64; m <<= 1) {
        s  += __shfl_xor(s, m, 64);
        sq += __shfl_xor(sq, m, 64);
    }
    __shared__ float ss[4], sqs[4];
    int wave = tid >> 6, lane = tid & 63;
    if (lane == 0) { ss[wave] = s; sqs[wave] = sq; }
    __syncthreads();
    s  = ss[0] + ss[1] + ss[2] + ss[3];
    sq = sqs[0] + sqs[1] + sqs[2] + sqs[3];
    float mu   = s * (1.0f / 768.0f);
    float var  = sq * (1.0f / 768.0f) - mu * mu;
    float rstd = rsqrtf(var + 1e-5f);
    __hip_bfloat16* yr = y + (size_t)row * E_;
    yr[tid]       = __float2bfloat16((v0 - mu) * rstd * w[tid]       + b[tid]);
    yr[tid + 256] = __float2bfloat16((v1 - mu) * rstd * w[tid + 256] + b[tid + 256]);
    yr[tid + 512] = __float2bfloat16((v2 - mu) * rstd * w[tid + 512] + b[tid + 512]);
}

// ---------------- Tversky attention (lane = j layout), bf16 out ----------------
#define KT_P 201
#define CH_ROWS 40
__global__ __launch_bounds__(256) void tversky_attn_kernel(const float* __restrict__ qkv,
                                                           __hip_bfloat16* __restrict__ o) {
    __shared__ float kT[64 * KT_P];
    __shared__ float ks_lds[200];
    __shared__ __align__(16) float q_lds[4][64];
    __shared__ __align__(16) float p_lds[4][200];

    const int tid  = threadIdx.x;
    const int wave = tid >> 6;
    const int lane = tid & 63;
    const int ch = blockIdx.x, hh = blockIdx.y, bb = blockIdx.z;
    const float* kbase = qkv + (size_t)bb * S_ * (3 * E_) + E_ + hh * DH_;

    for (int c = 0; c < (S_ * 64 + 255) / 256; ++c) {
        int idx = c * 256 + tid;
        int j = idx >> 6, d = idx & 63;
        bool valid = (j < S_);
        float val = 0.f;
        if (valid) {
            val = fmaxf(kbase[(size_t)j * (3 * E_) + d], 0.f);
            kT[d * KT_P + j] = val;
        }
        float s = val;
#pragma unroll
        for (int m = 1; m < 64; m <<= 1) s += __shfl_xor(s, m, 64);
        if (valid && lane == 0) ks_lds[j] = s;
    }
    __syncthreads();

    const int j0 = lane, j1 = lane + 64, j2 = lane + 128;
    const int j3 = (lane < 5) ? (lane + 192) : lane;

    const int i_begin = ch * CH_ROWS;
    const int i_end   = min(S_, i_begin + CH_ROWS);
    for (int i = i_begin + wave; i < i_end; i += 4) {
        const float* qrow = qkv + ((size_t)(bb * S_ + i)) * (3 * E_) + hh * DH_;
        float qp = fmaxf(qrow[lane], 0.f);
        float qs = qp;
#pragma unroll
        for (int m = 1; m < 64; m <<= 1) qs += __shfl_xor(qs, m, 64);
        q_lds[wave][lane] = qp;

        float l0 = 0.f, l1a = 0.f, l2a = 0.f, l3a = 0.f;
        const float* qw = &q_lds[wave][0];
#pragma unroll 8
        for (int d = 0; d < 64; ++d) {
            float qv = qw[d];
            const float* kr = &kT[d * KT_P];
            l0  += fabsf(qv - kr[j0]);
            l1a += fabsf(qv - kr[j1]);
            l2a += fabsf(qv - kr[j2]);
            l3a += fabsf(qv - kr[j3]);
        }
        float s0 = qs + ks_lds[j0];
        float s1 = qs + ks_lds[j1];
        float s2 = qs + ks_lds[j2];
        float s3 = qs + ks_lds[j3];
        float sc0 = (s0 - l0)  / (s0 + 2e-8f);
        float sc1 = (s1 - l1a) / (s1 + 2e-8f);
        float sc2 = (s2 - l2a) / (s2 + 2e-8f);
        float sc3 = (lane < 5) ? (s3 - l3a) / (s3 + 2e-8f) : -1e30f;

        float vmax = fmaxf(fmaxf(sc0, sc1), fmaxf(sc2, sc3));
#pragma unroll
        for (int m = 1; m < 64; m <<= 1) vmax = fmaxf(vmax, __shfl_xor(vmax, m, 64));
        float e0 = expf(sc0 - vmax);
        float e1 = expf(sc1 - vmax);
        float e2 = expf(sc2 - vmax);
        float e3 = (lane < 5) ? expf(sc3 - vmax) : 0.f;
        float sum = e0 + e1 + e2 + e3;
#pragma unroll
        for (int m = 1; m < 64; m <<= 1) sum += __shfl_xor(sum, m, 64);
        float inv = 1.f / sum;
        p_lds[wave][j0] = e0 * inv;
        p_lds[wave][j1] = e1 * inv;
        p_lds[wave][j2] = e2 * inv;
        if (lane < 5) p_lds[wave][lane + 192] = e3 * inv;

        const float* vbase = qkv + (size_t)bb * S_ * (3 * E_) + 2 * E_ + hh * DH_ + lane;
        float acc = 0.f;
#pragma unroll 4
        for (int j4 = 0; j4 < 196; j4 += 4) {
            float4 p4 = *(const float4*)&p_lds[wave][j4];
            acc += p4.x * vbase[(size_t)(j4 + 0) * (3 * E_)];
            acc += p4.y * vbase[(size_t)(j4 + 1) * (3 * E_)];
            acc += p4.z * vbase[(size_t)(j4 + 2) * (3 * E_)];
            acc += p4.w * vbase[(size_t)(j4 + 3) * (3 * E_)];
        }
        acc += p_lds[wave][196] * vbase[(size_t)196 * (3 * E_)];
        o[((size_t)(bb * S_) + i) * E_ + hh * DH_ + lane] = __float2bfloat16(acc);
    }
}

// ---------------- head: out[b,n] = ln[b,0,:] @ head_w + head_b ----------------
__global__ __launch_bounds__(256) void head_kernel(const __hip_bfloat16* __restrict__ ln,
                                                   const float* __restrict__ hw,
                                                   const float* __restrict__ hb,
                                                   float* __restrict__ out) {
    int b = blockIdx.y;
    int n = blockIdx.x * 256 + threadIdx.x;
    __shared__ float xr[E_];
    for (int e = threadIdx.x; e < E_; e += 256)
        xr[e] = __bfloat162float(ln[((size_t)b * S_) * E_ + e]);
    __syncthreads();
    if (n < OUT_) {
        float acc = hb[n];
        for (int e = 0; e < E_; ++e) acc += xr[e] * hw[(size_t)e * OUT_ + n];
        out[(size_t)b * OUT_ + n] = acc;
    }
}

extern "C" void kernel_launch(void* const* d_in, const int* in_sizes, int n_in,
                              void* d_out, int out_size, void* d_ws, size_t ws_size,
                              hipStream_t stream) {
    const float* x        = (const float*)d_in[0];
    const float* conv_w   = (const float*)d_in[1];
    const float* conv_b   = (const float*)d_in[2];
    const float* pos_e    = (const float*)d_in[3];
    const float* cls_t    = (const float*)d_in[4];
    const float* ln1_w    = (const float*)d_in[5];
    const float* ln1_b    = (const float*)d_in[6];
    const float* attn_w   = (const float*)d_in[7];
    const float* attn_b   = (const float*)d_in[8];
    const float* proj_w   = (const float*)d_in[9];
    const float* proj_b   = (const float*)d_in[10];
    const float* ln2_w    = (const float*)d_in[11];
    const float* ln2_b    = (const float*)d_in[12];
    const float* fc1_w    = (const float*)d_in[13];
    const float* fc1_b    = (const float*)d_in[14];
    const float* fc2_w    = (const float*)d_in[15];
    const float* fc2_b    = (const float*)d_in[16];
    const float* lnf_w    = (const float*)d_in[17];
    const float* lnf_b    = (const float*)d_in[18];
    const float* head_w   = (const float*)d_in[19];
    const float* head_b   = (const float*)d_in[20];
    float* out = (float*)d_out;

    // workspace layout
    float* h   = (float*)d_ws;                                    // 605184 f
    float* qkv = h + (size_t)ROWS_ * E_;                          // 1815552 f (aliases patch tmp)
    __hip_bfloat16* lnb = (__hip_bfloat16*)(qkv + (size_t)ROWS_ * 3 * E_);  // 605184
    __hip_bfloat16* ao  = lnb + (size_t)ROWS_ * E_;               // 605184
    __hip_bfloat16* hid = ao + (size_t)ROWS_ * E_;                // 2420736
    __hip_bfloat16* aim = hid + (size_t)ROWS_ * DFF_;             // 602112
    __hip_bfloat16* wt  = aim + (size_t)784 * E_;                 // up to 2359296

    // ---- patch embed (im2col + MFMA GEMM) ----
    im2col_kernel<<<(784 * 768) / 256, 256, 0, stream>>>(x, aim);
    cvt_bf16_kernel<<<(768 * 768 + 255) / 256, 256, 0, stream>>>(conv_w, wt, 768 * 768);
    {
        dim3 grid(E_ / 64, (784 + 63) / 64);
        gemm_mfma_kernel<<<grid, 256, 0, stream>>>(aim, wt, conv_b, nullptr, qkv, nullptr,
                                                   784, E_, E_, 0);
    }
    embed_finish_kernel<<<784, 256, 0, stream>>>(qkv, pos_e, h);
    cls_fill_kernel<<<B_, 256, 0, stream>>>(cls_t, h);

    for (int l = 0; l < LL_; ++l) {
        layernorm_kernel<<<ROWS_, 256, 0, stream>>>(h, ln1_w + l * E_, ln1_b + l * E_, lnb);
        {
            dim3 tg((3 * E_) / 32, E_ / 32);
            transpose_bf16_kernel<<<tg, 256, 0, stream>>>(attn_w + (size_t)l * E_ * 3 * E_, wt, E_, 3 * E_);
            dim3 grid((3 * E_) / 64, (ROWS_ + 63) / 64);
            gemm_mfma_kernel<<<grid, 256, 0, stream>>>(lnb, wt, attn_b + (size_t)l * 3 * E_,
                                                       nullptr, qkv, nullptr, ROWS_, 3 * E_, E_, 0);
        }
        {
            dim3 grid((S_ + CH_ROWS - 1) / CH_ROWS, NH_, B_);
            tversky_attn_kernel<<<grid, 256, 0, stream>>>(qkv, ao);
        }
        {
            dim3 tg(E_ / 32, E_ / 32);
            transpose_bf16_kernel<<<tg, 256, 0, stream>>>(proj_w + (size_t)l * E_ * E_, wt, E_, E_);
            dim3 grid(E_ / 64, (ROWS_ + 63) / 64);
            gemm_mfma_kernel<<<grid, 256, 0, stream>>>(ao, wt, proj_b + (size_t)l * E_,
                                                       h, h, nullptr, ROWS_, E_, E_, 0);
        }
        layernorm_kernel<<<ROWS_, 256, 0, stream>>>(h, ln2_w + l * E_, ln2_b + l * E_, lnb);
        {
            dim3 tg(DFF_ / 32, E_ / 32);
            transpose_bf16_kernel<<<tg, 256, 0, stream>>>(fc1_w + (size_t)l * E_ * DFF_, wt, E_, DFF_);
            dim3 grid(DFF_ / 64, (ROWS_ + 63) / 64);
            gemm_mfma_kernel<<<grid, 256, 0, stream>>>(lnb, wt, fc1_b + (size_t)l * DFF_,
                                                       nullptr, nullptr, hid, ROWS_, DFF_, E_, 1);
        }
        {
            dim3 tg(E_ / 32, DFF_ / 32);
            transpose_bf16_kernel<<<tg, 256, 0, stream>>>(fc2_w + (size_t)l * DFF_ * E_, wt, DFF_, E_);
            dim3 grid(E_ / 64, (ROWS_ + 63) / 64);
            gemm_mfma_kernel<<<grid, 256, 0, stream>>>(hid, wt, fc2_b + (size_t)l * E_,
                                                       h, h, nullptr, ROWS_, E_, DFF_, 0);
        }
    }

    layernorm_kernel<<<ROWS_, 256, 0, stream>>>(h, lnf_w, lnf_b, lnb);
    {
        dim3 grid((OUT_ + 255) / 256, B_);
        head_kernel<<<grid, 256, 0, stream>>>(lnb, head_w, head_b, out);
    }
}

// Round 4
// 662.890 us; speedup vs baseline: 3.1404x; 1.1333x over previous
//
#include <hip/hip_runtime.h>
#include <hip/hip_bf16.h>
#include <math.h>

// Shapes
#define B_  4
#define E_  768
#define NH_ 12
#define DH_ 64
#define LL_ 2
#define DFF_ 3072
#define OUT_ 1000
#define S_  197
#define ROWS_ 788          // B_*S_

typedef __bf16 bf16x8_t __attribute__((ext_vector_type(8)));
typedef float f32x4_t __attribute__((ext_vector_type(4)));

__device__ __forceinline__ float gelu_f(float x) {
    float x3 = x * x * x;
    return 0.5f * x * (1.0f + tanhf(0.7978845608028654f * (x + 0.044715f * x3)));
}

// ---------------- im2col to bf16 ----------------
__global__ __launch_bounds__(256) void im2col_kernel(const float* __restrict__ x,
                                                     __hip_bfloat16* __restrict__ aim) {
    int id = blockIdx.x * 256 + threadIdx.x;        // 784*768 exact
    int row = id / 768, k = id - row * 768;
    int b = row / 196, pr = row - b * 196;
    int hp = pr / 14, wp = pr - hp * 14;
    int c = k >> 8, rem = k & 255, p = rem >> 4, q = rem & 15;
    aim[id] = __float2bfloat16(x[(((size_t)(b * 3 + c) * 224) + hp * 16 + p) * 224 + wp * 16 + q]);
}

__global__ __launch_bounds__(256) void cvt_bf16_kernel(const float* __restrict__ in,
                                                       __hip_bfloat16* __restrict__ out, int n) {
    int i = blockIdx.x * 256 + threadIdx.x;
    if (i < n) out[i] = __float2bfloat16(in[i]);
}

// ---------------- tiled transpose + convert: in[K,N] fp32 -> out[N,K] bf16 ----------------
__global__ __launch_bounds__(256) void transpose_bf16_kernel(const float* __restrict__ in,
                                                             __hip_bfloat16* __restrict__ out,
                                                             int K, int N) {
    __shared__ __hip_bfloat16 t[32][33];
    int kb = blockIdx.y * 32, nb = blockIdx.x * 32;
    int tx = threadIdx.x & 31, ty = threadIdx.x >> 5;
#pragma unroll
    for (int r = 0; r < 32; r += 8)
        t[ty + r][tx] = __float2bfloat16(in[(size_t)(kb + ty + r) * N + nb + tx]);
    __syncthreads();
#pragma unroll
    for (int r = 0; r < 32; r += 8)
        out[(size_t)(nb + ty + r) * K + kb + tx] = t[tx][ty + r];
}

// ---------------- MFMA GEMM ----------------
#define BK 64
#define AP 72
__global__ __launch_bounds__(256) void gemm_mfma_kernel(const __hip_bfloat16* __restrict__ A,
                                                        const __hip_bfloat16* __restrict__ WT,
                                                        const float* __restrict__ bias,
                                                        const float* __restrict__ res,
                                                        float* __restrict__ Cf,
                                                        __hip_bfloat16* __restrict__ Cb,
                                                        int M, int N, int K, int act) {
    __shared__ __align__(16) ushort Asb[64 * AP];
    __shared__ __align__(16) ushort Bsb[64 * AP];
    const int tid = threadIdx.x;
    const int wave = tid >> 6, lane = tid & 63;
    const int quad = lane >> 4, l15 = lane & 15;
    const int wm = wave >> 1, wn = wave & 1;
    const int m0 = blockIdx.y * 64, n0 = blockIdx.x * 64;

    f32x4_t acc[2][2] = {};

    const int c0r = tid >> 3,         c0o = (tid & 7) * 8;
    const int c1r = (tid + 256) >> 3, c1o = c0o;

    for (int k0 = 0; k0 < K; k0 += BK) {
        __syncthreads();
        {
            uint4 v = make_uint4(0, 0, 0, 0);
            int gm = m0 + c0r;
            if (gm < M) v = *(const uint4*)&A[(size_t)gm * K + k0 + c0o];
            *(uint4*)&Asb[c0r * AP + c0o] = v;
            v = make_uint4(0, 0, 0, 0);
            gm = m0 + c1r;
            if (gm < M) v = *(const uint4*)&A[(size_t)gm * K + k0 + c1o];
            *(uint4*)&Asb[c1r * AP + c1o] = v;
        }
        {
            uint4 v = *(const uint4*)&WT[(size_t)(n0 + c0r) * K + k0 + c0o];
            *(uint4*)&Bsb[c0r * AP + c0o] = v;
            v = *(const uint4*)&WT[(size_t)(n0 + c1r) * K + k0 + c1o];
            *(uint4*)&Bsb[c1r * AP + c1o] = v;
        }
        __syncthreads();
#pragma unroll
        for (int ks = 0; ks < BK; ks += 32) {
            bf16x8_t a0 = *(const bf16x8_t*)&Asb[(32 * wm + l15) * AP + ks + 8 * quad];
            bf16x8_t a1 = *(const bf16x8_t*)&Asb[(32 * wm + 16 + l15) * AP + ks + 8 * quad];
            bf16x8_t b0 = *(const bf16x8_t*)&Bsb[(32 * wn + l15) * AP + ks + 8 * quad];
            bf16x8_t b1 = *(const bf16x8_t*)&Bsb[(32 * wn + 16 + l15) * AP + ks + 8 * quad];
            acc[0][0] = __builtin_amdgcn_mfma_f32_16x16x32_bf16(a0, b0, acc[0][0], 0, 0, 0);
            acc[0][1] = __builtin_amdgcn_mfma_f32_16x16x32_bf16(a0, b1, acc[0][1], 0, 0, 0);
            acc[1][0] = __builtin_amdgcn_mfma_f32_16x16x32_bf16(a1, b0, acc[1][0], 0, 0, 0);
            acc[1][1] = __builtin_amdgcn_mfma_f32_16x16x32_bf16(a1, b1, acc[1][1], 0, 0, 0);
        }
    }

#pragma unroll
    for (int mi = 0; mi < 2; ++mi)
#pragma unroll
        for (int ni = 0; ni < 2; ++ni) {
            int gn = n0 + 32 * wn + 16 * ni + l15;
#pragma unroll
            for (int r = 0; r < 4; ++r) {
                int gm = m0 + 32 * wm + 16 * mi + quad * 4 + r;
                if (gm < M) {
                    float v = acc[mi][ni][r] + bias[gn];
                    if (act == 1) v = gelu_f(v);
                    if (res) v += res[(size_t)gm * N + gn];
                    if (Cf) Cf[(size_t)gm * N + gn] = v;
                    else    Cb[(size_t)gm * N + gn] = __float2bfloat16(v);
                }
            }
        }
}

// ---------------- patch-embed finish + cls ----------------
__global__ __launch_bounds__(256) void embed_finish_kernel(const float* __restrict__ tmp,
                                                           const float* __restrict__ pe,
                                                           float* __restrict__ h) {
    int row = blockIdx.x;
    int b = row / 196, pr = row - b * 196;
    for (int e = threadIdx.x; e < E_; e += 256)
        h[((size_t)(b * S_ + 1 + pr)) * E_ + e] = tmp[(size_t)row * E_ + e] + pe[(size_t)pr * E_ + e];
}

__global__ __launch_bounds__(256) void cls_fill_kernel(const float* __restrict__ ct,
                                                       float* __restrict__ h) {
    int b = blockIdx.x;
    int t = threadIdx.x;
    h[(size_t)b * S_ * E_ + t]       = ct[t];
    h[(size_t)b * S_ * E_ + t + 256] = ct[t + 256];
    h[(size_t)b * S_ * E_ + t + 512] = ct[t + 512];
}

// ---------------- LayerNorm (fp32 in, bf16 out) ----------------
__global__ __launch_bounds__(256) void layernorm_kernel(const float* __restrict__ x,
                                                        const float* __restrict__ w,
                                                        const float* __restrict__ b,
                                                        __hip_bfloat16* __restrict__ y) {
    int row = blockIdx.x;
    const float* xr = x + (size_t)row * E_;
    int tid = threadIdx.x;
    float v0 = xr[tid], v1 = xr[tid + 256], v2 = xr[tid + 512];
    float s  = v0 + v1 + v2;
    float sq = v0 * v0 + v1 * v1 + v2 * v2;
#pragma unroll
    for (int m = 1; m < 64; m <<= 1) {
        s  += __shfl_xor(s, m, 64);
        sq += __shfl_xor(sq, m, 64);
    }
    __shared__ float ss[4], sqs[4];
    int wave = tid >> 6, lane = tid & 63;
    if (lane == 0) { ss[wave] = s; sqs[wave] = sq; }
    __syncthreads();
    s  = ss[0] + ss[1] + ss[2] + ss[3];
    sq = sqs[0] + sqs[1] + sqs[2] + sqs[3];
    float mu   = s * (1.0f / 768.0f);
    float var  = sq * (1.0f / 768.0f) - mu * mu;
    float rstd = rsqrtf(var + 1e-5f);
    __hip_bfloat16* yr = y + (size_t)row * E_;
    yr[tid]       = __float2bfloat16((v0 - mu) * rstd * w[tid]       + b[tid]);
    yr[tid + 256] = __float2bfloat16((v1 - mu) * rstd * w[tid + 256] + b[tid + 256]);
    yr[tid + 512] = __float2bfloat16((v2 - mu) * rstd * w[tid + 512] + b[tid + 512]);
}

// ---------------- attention prep: ktg[head][d][j] = relu(K), ksg[head][j] ----------------
#define KT_P 201
#define KT_GP 200
__global__ __launch_bounds__(256) void attn_prep_kernel(const float* __restrict__ qkv,
                                                        float* __restrict__ ktg,
                                                        float* __restrict__ ksg) {
    __shared__ float kT[64 * KT_P];
    const int tid = threadIdx.x;
    const int lane = tid & 63;
    const int hh = blockIdx.x, bb = blockIdx.y;
    const int head = bb * NH_ + hh;
    const float* kbase = qkv + (size_t)bb * S_ * (3 * E_) + E_ + hh * DH_;

    for (int c = 0; c < (S_ * 64 + 255) / 256; ++c) {
        int idx = c * 256 + tid;
        int j = idx >> 6, d = idx & 63;
        bool valid = (j < S_);
        float val = 0.f;
        if (valid) {
            val = fmaxf(kbase[(size_t)j * (3 * E_) + d], 0.f);
            kT[d * KT_P + j] = val;
        }
        float s = val;
#pragma unroll
        for (int m = 1; m < 64; m <<= 1) s += __shfl_xor(s, m, 64);
        if (valid && lane == 0) ksg[(size_t)head * KT_GP + j] = s;
    }
    __syncthreads();
    float* orow = ktg + (size_t)head * 64 * KT_GP;
    for (int idx = tid; idx < 64 * KT_GP; idx += 256) {
        int d = idx / KT_GP, j = idx - d * KT_GP;
        orow[idx] = (j < S_) ? kT[d * KT_P + j] : 0.f;
    }
}

// ---------------- Tversky attention main: one wave per 4 q-rows ----------------
// score(i,j) = (qs+ks-l1)/(qs+ks+2eps)  [exact for a=b=0.5,g=1]
#define RW 4
#define CHUNK (4 * RW)     // rows per block = 16
__global__ __launch_bounds__(256) void tversky_attn_kernel(const float* __restrict__ qkv,
                                                           const float* __restrict__ ktg,
                                                           const float* __restrict__ ksg,
                                                           __hip_bfloat16* __restrict__ o) {
    __shared__ __align__(16) float q_lds[4][RW][64];     // 4 KB
    __shared__ __align__(16) float p_lds[4][RW][200];    // 12.8 KB

    const int tid  = threadIdx.x;
    const int wave = tid >> 6;
    const int lane = tid & 63;
    const int ch = blockIdx.x, hh = blockIdx.y, bb = blockIdx.z;
    const int head = bb * NH_ + hh;
    const int i0 = ch * CHUNK + wave * RW;
    if (i0 >= S_) return;                    // no __syncthreads below: safe

    // load q rows, qs
    float qs[RW];
#pragma unroll
    for (int r = 0; r < RW; ++r) {
        int i = i0 + r;
        float qp = 0.f;
        if (i < S_)
            qp = fmaxf(qkv[((size_t)(bb * S_ + i)) * (3 * E_) + hh * DH_ + lane], 0.f);
        float s = qp;
#pragma unroll
        for (int m = 1; m < 64; m <<= 1) s += __shfl_xor(s, m, 64);
        qs[r] = s;
        q_lds[wave][r][lane] = qp;
    }

    const int j0 = lane, j1 = lane + 64, j2 = lane + 128;
    const int j3c = (lane < 5) ? (lane + 192) : 196;     // clamped

    const float* ksrow = ksg + (size_t)head * KT_GP;
    const float ks0 = ksrow[j0], ks1 = ksrow[j1], ks2 = ksrow[j2], ks3 = ksrow[j3c];

    // l1 accumulation: stream kT rows, amortized over RW q-rows
    const float* ktrow = ktg + (size_t)head * 64 * KT_GP;
    float l[4][RW] = {};
#pragma unroll 4
    for (int d4 = 0; d4 < 16; ++d4) {
        float4 qv[RW];
#pragma unroll
        for (int r = 0; r < RW; ++r) qv[r] = *(const float4*)&q_lds[wave][r][d4 * 4];
#pragma unroll
        for (int dd = 0; dd < 4; ++dd) {
            const float* kr = ktrow + (size_t)(d4 * 4 + dd) * KT_GP;
            float k0 = kr[j0], k1 = kr[j1], k2 = kr[j2], k3 = kr[j3c];
#pragma unroll
            for (int r = 0; r < RW; ++r) {
                float q = (dd == 0) ? qv[r].x : (dd == 1) ? qv[r].y : (dd == 2) ? qv[r].z : qv[r].w;
                l[0][r] += fabsf(q - k0);
                l[1][r] += fabsf(q - k1);
                l[2][r] += fabsf(q - k2);
                l[3][r] += fabsf(q - k3);
            }
        }
    }

    // scores + softmax per row
#pragma unroll
    for (int r = 0; r < RW; ++r) {
        if (i0 + r >= S_) break;
        float s0 = qs[r] + ks0, s1 = qs[r] + ks1, s2 = qs[r] + ks2, s3 = qs[r] + ks3;
        float sc0 = (s0 - l[0][r]) / (s0 + 2e-8f);
        float sc1 = (s1 - l[1][r]) / (s1 + 2e-8f);
        float sc2 = (s2 - l[2][r]) / (s2 + 2e-8f);
        float sc3 = (lane < 5) ? (s3 - l[3][r]) / (s3 + 2e-8f) : -1e30f;
        float vmax = fmaxf(fmaxf(sc0, sc1), fmaxf(sc2, sc3));
#pragma unroll
        for (int m = 1; m < 64; m <<= 1) vmax = fmaxf(vmax, __shfl_xor(vmax, m, 64));
        float e0 = expf(sc0 - vmax);
        float e1 = expf(sc1 - vmax);
        float e2 = expf(sc2 - vmax);
        float e3 = (lane < 5) ? expf(sc3 - vmax) : 0.f;
        float sum = e0 + e1 + e2 + e3;
#pragma unroll
        for (int m = 1; m < 64; m <<= 1) sum += __shfl_xor(sum, m, 64);
        float inv = 1.f / sum;
        p_lds[wave][r][j0] = e0 * inv;
        p_lds[wave][r][j1] = e1 * inv;
        p_lds[wave][r][j2] = e2 * inv;
        if (lane < 5) p_lds[wave][r][lane + 192] = e3 * inv;
    }

    // PV: lane = d; v loads amortized over RW rows
    const float* vbase = qkv + (size_t)bb * S_ * (3 * E_) + 2 * E_ + hh * DH_ + lane;
    float acc[RW] = {};
#pragma unroll 4
    for (int j4 = 0; j4 < 196; j4 += 4) {
        float v0 = vbase[(size_t)(j4 + 0) * (3 * E_)];
        float v1 = vbase[(size_t)(j4 + 1) * (3 * E_)];
        float v2 = vbase[(size_t)(j4 + 2) * (3 * E_)];
        float v3 = vbase[(size_t)(j4 + 3) * (3 * E_)];
#pragma unroll
        for (int r = 0; r < RW; ++r) {
            float4 p4 = *(const float4*)&p_lds[wave][r][j4];
            acc[r] += p4.x * v0 + p4.y * v1 + p4.z * v2 + p4.w * v3;
        }
    }
    float v196 = vbase[(size_t)196 * (3 * E_)];
#pragma unroll
    for (int r = 0; r < RW; ++r) {
        int i = i0 + r;
        if (i < S_) {
            float a = acc[r] + p_lds[wave][r][196] * v196;
            o[((size_t)(bb * S_) + i) * E_ + hh * DH_ + lane] = __float2bfloat16(a);
        }
    }
}

// ---------------- head ----------------
__global__ __launch_bounds__(256) void head_kernel(const __hip_bfloat16* __restrict__ ln,
                                                   const float* __restrict__ hw,
                                                   const float* __restrict__ hb,
                                                   float* __restrict__ out) {
    int b = blockIdx.y;
    int n = blockIdx.x * 256 + threadIdx.x;
    __shared__ float xr[E_];
    for (int e = threadIdx.x; e < E_; e += 256)
        xr[e] = __bfloat162float(ln[((size_t)b * S_) * E_ + e]);
    __syncthreads();
    if (n < OUT_) {
        float acc = hb[n];
        for (int e = 0; e < E_; ++e) acc += xr[e] * hw[(size_t)e * OUT_ + n];
        out[(size_t)b * OUT_ + n] = acc;
    }
}

extern "C" void kernel_launch(void* const* d_in, const int* in_sizes, int n_in,
                              void* d_out, int out_size, void* d_ws, size_t ws_size,
                              hipStream_t stream) {
    const float* x        = (const float*)d_in[0];
    const float* conv_w   = (const float*)d_in[1];
    const float* conv_b   = (const float*)d_in[2];
    const float* pos_e    = (const float*)d_in[3];
    const float* cls_t    = (const float*)d_in[4];
    const float* ln1_w    = (const float*)d_in[5];
    const float* ln1_b    = (const float*)d_in[6];
    const float* attn_w   = (const float*)d_in[7];
    const float* attn_b   = (const float*)d_in[8];
    const float* proj_w   = (const float*)d_in[9];
    const float* proj_b   = (const float*)d_in[10];
    const float* ln2_w    = (const float*)d_in[11];
    const float* ln2_b    = (const float*)d_in[12];
    const float* fc1_w    = (const float*)d_in[13];
    const float* fc1_b    = (const float*)d_in[14];
    const float* fc2_w    = (const float*)d_in[15];
    const float* fc2_b    = (const float*)d_in[16];
    const float* lnf_w    = (const float*)d_in[17];
    const float* lnf_b    = (const float*)d_in[18];
    const float* head_w   = (const float*)d_in[19];
    const float* head_b   = (const float*)d_in[20];
    float* out = (float*)d_out;

    // workspace layout
    float* h   = (float*)d_ws;                                    // 605184 f
    float* qkv = h + (size_t)ROWS_ * E_;                          // 1815552 f
    __hip_bfloat16* lnb = (__hip_bfloat16*)(qkv + (size_t)ROWS_ * 3 * E_);
    __hip_bfloat16* ao  = lnb + (size_t)ROWS_ * E_;
    __hip_bfloat16* hid = ao + (size_t)ROWS_ * E_;
    __hip_bfloat16* aim = hid + (size_t)ROWS_ * DFF_;
    __hip_bfloat16* wt  = aim + (size_t)784 * E_;                 // up to 2359296 bf16
    float* ktg = (float*)(wt + (size_t)2359296);                  // 48*64*200 f
    float* ksg = ktg + (size_t)48 * 64 * KT_GP;                   // 48*200 f

    // ---- patch embed ----
    im2col_kernel<<<(784 * 768) / 256, 256, 0, stream>>>(x, aim);
    cvt_bf16_kernel<<<(768 * 768 + 255) / 256, 256, 0, stream>>>(conv_w, wt, 768 * 768);
    {
        dim3 grid(E_ / 64, (784 + 63) / 64);
        gemm_mfma_kernel<<<grid, 256, 0, stream>>>(aim, wt, conv_b, nullptr, qkv, nullptr,
                                                   784, E_, E_, 0);
    }
    embed_finish_kernel<<<784, 256, 0, stream>>>(qkv, pos_e, h);
    cls_fill_kernel<<<B_, 256, 0, stream>>>(cls_t, h);

    for (int l = 0; l < LL_; ++l) {
        layernorm_kernel<<<ROWS_, 256, 0, stream>>>(h, ln1_w + l * E_, ln1_b + l * E_, lnb);
        {
            dim3 tg((3 * E_) / 32, E_ / 32);
            transpose_bf16_kernel<<<tg, 256, 0, stream>>>(attn_w + (size_t)l * E_ * 3 * E_, wt, E_, 3 * E_);
            dim3 grid((3 * E_) / 64, (ROWS_ + 63) / 64);
            gemm_mfma_kernel<<<grid, 256, 0, stream>>>(lnb, wt, attn_b + (size_t)l * 3 * E_,
                                                       nullptr, qkv, nullptr, ROWS_, 3 * E_, E_, 0);
        }
        {
            attn_prep_kernel<<<dim3(NH_, B_), 256, 0, stream>>>(qkv, ktg, ksg);
            dim3 grid((S_ + CHUNK - 1) / CHUNK, NH_, B_);       // 13 x 12 x 4 = 624 blocks
            tversky_attn_kernel<<<grid, 256, 0, stream>>>(qkv, ktg, ksg, ao);
        }
        {
            dim3 tg(E_ / 32, E_ / 32);
            transpose_bf16_kernel<<<tg, 256, 0, stream>>>(proj_w + (size_t)l * E_ * E_, wt, E_, E_);
            dim3 grid(E_ / 64, (ROWS_ + 63) / 64);
            gemm_mfma_kernel<<<grid, 256, 0, stream>>>(ao, wt, proj_b + (size_t)l * E_,
                                                       h, h, nullptr, ROWS_, E_, E_, 0);
        }
        layernorm_kernel<<<ROWS_, 256, 0, stream>>>(h, ln2_w + l * E_, ln2_b + l * E_, lnb);
        {
            dim3 tg(DFF_ / 32, E_ / 32);
            transpose_bf16_kernel<<<tg, 256, 0, stream>>>(fc1_w + (size_t)l * E_ * DFF_, wt, E_, DFF_);
            dim3 grid(DFF_ / 64, (ROWS_ + 63) / 64);
            gemm_mfma_kernel<<<grid, 256, 0, stream>>>(lnb, wt, fc1_b + (size_t)l * DFF_,
                                                       nullptr, nullptr, hid, ROWS_, DFF_, E_, 1);
        }
        {
            dim3 tg(E_ / 32, DFF_ / 32);
            transpose_bf16_kernel<<<tg, 256, 0, stream>>>(fc2_w + (size_t)l * DFF_ * E_, wt, DFF_, E_);
            dim3 grid(E_ / 64, (ROWS_ + 63) / 64);
            gemm_mfma_kernel<<<grid, 256, 0, stream>>>(hid, wt, fc2_b + (size_t)l * E_,
                                                       h, h, nullptr, ROWS_, E_, DFF_, 0);
        }
    }

    layernorm_kernel<<<ROWS_, 256, 0, stream>>>(h, lnf_w, lnf_b, lnb);
    {
        dim3 grid((OUT_ + 255) / 256, B_);
        head_kernel<<<grid, 256, 0, stream>>>(lnb, head_w, head_b, out);
    }
}

// Round 5
// 465.362 us; speedup vs baseline: 4.4734x; 1.4245x over previous
//
#include <hip/hip_runtime.h>
#include <hip/hip_bf16.h>
#include <math.h>

// Shapes
#define B_  4
#define E_  768
#define NH_ 12
#define DH_ 64
#define LL_ 2
#define DFF_ 3072
#define OUT_ 1000
#define S_  197
#define ROWS_ 788          // B_*S_

typedef __bf16 bf16x8_t __attribute__((ext_vector_type(8)));
typedef float f32x4_t __attribute__((ext_vector_type(4)));

__device__ __forceinline__ float gelu_f(float x) {
    float x3 = x * x * x;
    return 0.5f * x * (1.0f + tanhf(0.7978845608028654f * (x + 0.044715f * x3)));
}

// ---------------- im2col to bf16 ----------------
__global__ __launch_bounds__(256) void im2col_kernel(const float* __restrict__ x,
                                                     __hip_bfloat16* __restrict__ aim) {
    int id = blockIdx.x * 256 + threadIdx.x;        // 784*768 exact
    int row = id / 768, k = id - row * 768;
    int b = row / 196, pr = row - b * 196;
    int hp = pr / 14, wp = pr - hp * 14;
    int c = k >> 8, rem = k & 255, p = rem >> 4, q = rem & 15;
    aim[id] = __float2bfloat16(x[(((size_t)(b * 3 + c) * 224) + hp * 16 + p) * 224 + wp * 16 + q]);
}

__global__ __launch_bounds__(256) void cvt_bf16_kernel(const float* __restrict__ in,
                                                       __hip_bfloat16* __restrict__ out, int n) {
    int i = blockIdx.x * 256 + threadIdx.x;
    if (i < n) out[i] = __float2bfloat16(in[i]);
}

// ---------------- tiled transpose + convert: in[K,N] fp32 -> out[N,K] bf16 ----------------
__global__ __launch_bounds__(256) void transpose_bf16_kernel(const float* __restrict__ in,
                                                             __hip_bfloat16* __restrict__ out,
                                                             int K, int N) {
    __shared__ __hip_bfloat16 t[32][33];
    int kb = blockIdx.y * 32, nb = blockIdx.x * 32;
    int tx = threadIdx.x & 31, ty = threadIdx.x >> 5;
#pragma unroll
    for (int r = 0; r < 32; r += 8)
        t[ty + r][tx] = __float2bfloat16(in[(size_t)(kb + ty + r) * N + nb + tx]);
    __syncthreads();
#pragma unroll
    for (int r = 0; r < 32; r += 8)
        out[(size_t)(nb + ty + r) * K + kb + tx] = t[tx][ty + r];
}

// ---------------- MFMA GEMM with register-prefetch pipeline + optional split-K ----------------
// A: [M,K] bf16. WT: [N,K] bf16. KS slices along K via blockIdx.z (K % (KS*BK) == 0 assumed).
// If part != nullptr: write raw fp32 partials (no bias/act/res) to part[z][M][N].
#define BK 64
#define AP 72
__global__ __launch_bounds__(256) void gemm_mfma_kernel(const __hip_bfloat16* __restrict__ A,
                                                        const __hip_bfloat16* __restrict__ WT,
                                                        const float* __restrict__ bias,
                                                        const float* __restrict__ res,
                                                        float* __restrict__ Cf,
                                                        __hip_bfloat16* __restrict__ Cb,
                                                        float* __restrict__ part,
                                                        int M, int N, int K, int act, int KS) {
    __shared__ __align__(16) ushort Asb[64 * AP];
    __shared__ __align__(16) ushort Bsb[64 * AP];
    const int tid = threadIdx.x;
    const int wave = tid >> 6, lane = tid & 63;
    const int quad = lane >> 4, l15 = lane & 15;
    const int wm = wave >> 1, wn = wave & 1;
    const int m0 = blockIdx.y * 64, n0 = blockIdx.x * 64;

    const int Kc   = K / KS;
    const int kbeg = blockIdx.z * Kc;
    const int n_it = Kc / BK;

    f32x4_t acc[2][2] = {};

    const int c0r = tid >> 3,         c0o = (tid & 7) * 8;
    const int c1r = (tid + 256) >> 3, c1o = c0o;

    uint4 pa0, pa1, pb0, pb1;
    auto load_tile = [&](int kk) {
        pa0 = make_uint4(0, 0, 0, 0);
        pa1 = pa0;
        int gm = m0 + c0r;
        if (gm < M) pa0 = *(const uint4*)&A[(size_t)gm * K + kk + c0o];
        gm = m0 + c1r;
        if (gm < M) pa1 = *(const uint4*)&A[(size_t)gm * K + kk + c1o];
        pb0 = *(const uint4*)&WT[(size_t)(n0 + c0r) * K + kk + c0o];
        pb1 = *(const uint4*)&WT[(size_t)(n0 + c1r) * K + kk + c1o];
    };

    load_tile(kbeg);
    for (int it = 0; it < n_it; ++it) {
        __syncthreads();
        *(uint4*)&Asb[c0r * AP + c0o] = pa0;
        *(uint4*)&Asb[c1r * AP + c1o] = pa1;
        *(uint4*)&Bsb[c0r * AP + c0o] = pb0;
        *(uint4*)&Bsb[c1r * AP + c1o] = pb1;
        if (it + 1 < n_it) load_tile(kbeg + (it + 1) * BK);   // prefetch during MFMA phase
        __syncthreads();
#pragma unroll
        for (int ks = 0; ks < BK; ks += 32) {
            bf16x8_t a0 = *(const bf16x8_t*)&Asb[(32 * wm + l15) * AP + ks + 8 * quad];
            bf16x8_t a1 = *(const bf16x8_t*)&Asb[(32 * wm + 16 + l15) * AP + ks + 8 * quad];
            bf16x8_t b0 = *(const bf16x8_t*)&Bsb[(32 * wn + l15) * AP + ks + 8 * quad];
            bf16x8_t b1 = *(const bf16x8_t*)&Bsb[(32 * wn + 16 + l15) * AP + ks + 8 * quad];
            acc[0][0] = __builtin_amdgcn_mfma_f32_16x16x32_bf16(a0, b0, acc[0][0], 0, 0, 0);
            acc[0][1] = __builtin_amdgcn_mfma_f32_16x16x32_bf16(a0, b1, acc[0][1], 0, 0, 0);
            acc[1][0] = __builtin_amdgcn_mfma_f32_16x16x32_bf16(a1, b0, acc[1][0], 0, 0, 0);
            acc[1][1] = __builtin_amdgcn_mfma_f32_16x16x32_bf16(a1, b1, acc[1][1], 0, 0, 0);
        }
    }

    if (part) {
        float* P = part + (size_t)blockIdx.z * M * N;
#pragma unroll
        for (int mi = 0; mi < 2; ++mi)
#pragma unroll
            for (int ni = 0; ni < 2; ++ni) {
                int gn = n0 + 32 * wn + 16 * ni + l15;
#pragma unroll
                for (int r = 0; r < 4; ++r) {
                    int gm = m0 + 32 * wm + 16 * mi + quad * 4 + r;
                    if (gm < M) P[(size_t)gm * N + gn] = acc[mi][ni][r];
                }
            }
        return;
    }

#pragma unroll
    for (int mi = 0; mi < 2; ++mi)
#pragma unroll
        for (int ni = 0; ni < 2; ++ni) {
            int gn = n0 + 32 * wn + 16 * ni + l15;
#pragma unroll
            for (int r = 0; r < 4; ++r) {
                int gm = m0 + 32 * wm + 16 * mi + quad * 4 + r;
                if (gm < M) {
                    float v = acc[mi][ni][r] + bias[gn];
                    if (act == 1) v = gelu_f(v);
                    if (res) v += res[(size_t)gm * N + gn];
                    if (Cf) Cf[(size_t)gm * N + gn] = v;
                    else    Cb[(size_t)gm * N + gn] = __float2bfloat16(v);
                }
            }
        }
}

// ---------------- split-K reduce + epilogue (fp32 out) ----------------
__global__ __launch_bounds__(256) void splitk_reduce_kernel(const float* __restrict__ part,
                                                            const float* __restrict__ bias,
                                                            const float* __restrict__ res,
                                                            float* __restrict__ Cf,
                                                            int M, int N, int KS) {
    int i = blockIdx.x * 256 + threadIdx.x;
    if (i >= M * N) return;
    int n = i % N;
    float v = bias[n];
    for (int s = 0; s < KS; ++s) v += part[(size_t)s * M * N + i];
    if (res) v += res[i];
    Cf[i] = v;
}

// ---------------- patch-embed finish + cls ----------------
__global__ __launch_bounds__(256) void embed_finish_kernel(const float* __restrict__ tmp,
                                                           const float* __restrict__ pe,
                                                           float* __restrict__ h) {
    int row = blockIdx.x;
    int b = row / 196, pr = row - b * 196;
    for (int e = threadIdx.x; e < E_; e += 256)
        h[((size_t)(b * S_ + 1 + pr)) * E_ + e] = tmp[(size_t)row * E_ + e] + pe[(size_t)pr * E_ + e];
}

__global__ __launch_bounds__(256) void cls_fill_kernel(const float* __restrict__ ct,
                                                       float* __restrict__ h) {
    int b = blockIdx.x;
    int t = threadIdx.x;
    h[(size_t)b * S_ * E_ + t]       = ct[t];
    h[(size_t)b * S_ * E_ + t + 256] = ct[t + 256];
    h[(size_t)b * S_ * E_ + t + 512] = ct[t + 512];
}

// ---------------- LayerNorm (fp32 in, bf16 out) ----------------
__global__ __launch_bounds__(256) void layernorm_kernel(const float* __restrict__ x,
                                                        const float* __restrict__ w,
                                                        const float* __restrict__ b,
                                                        __hip_bfloat16* __restrict__ y) {
    int row = blockIdx.x;
    const float* xr = x + (size_t)row * E_;
    int tid = threadIdx.x;
    float v0 = xr[tid], v1 = xr[tid + 256], v2 = xr[tid + 512];
    float s  = v0 + v1 + v2;
    float sq = v0 * v0 + v1 * v1 + v2 * v2;
#pragma unroll
    for (int m = 1; m < 64; m <<= 1) {
        s  += __shfl_xor(s, m, 64);
        sq += __shfl_xor(sq, m, 64);
    }
    __shared__ float ss[4], sqs[4];
    int wave = tid >> 6, lane = tid & 63;
    if (lane == 0) { ss[wave] = s; sqs[wave] = sq; }
    __syncthreads();
    s  = ss[0] + ss[1] + ss[2] + ss[3];
    sq = sqs[0] + sqs[1] + sqs[2] + sqs[3];
    float mu   = s * (1.0f / 768.0f);
    float var  = sq * (1.0f / 768.0f) - mu * mu;
    float rstd = rsqrtf(var + 1e-5f);
    __hip_bfloat16* yr = y + (size_t)row * E_;
    yr[tid]       = __float2bfloat16((v0 - mu) * rstd * w[tid]       + b[tid]);
    yr[tid + 256] = __float2bfloat16((v1 - mu) * rstd * w[tid + 256] + b[tid + 256]);
    yr[tid + 512] = __float2bfloat16((v2 - mu) * rstd * w[tid + 512] + b[tid + 512]);
}

// ---------------- attention prep: ktg[head][d][j] = relu(K), ksg[head][j] ----------------
#define KT_P 201
#define KT_GP 200
__global__ __launch_bounds__(256) void attn_prep_kernel(const float* __restrict__ qkv,
                                                        float* __restrict__ ktg,
                                                        float* __restrict__ ksg) {
    __shared__ float kT[64 * KT_P];
    const int tid = threadIdx.x;
    const int lane = tid & 63;
    const int hh = blockIdx.x, bb = blockIdx.y;
    const int head = bb * NH_ + hh;
    const float* kbase = qkv + (size_t)bb * S_ * (3 * E_) + E_ + hh * DH_;

    for (int c = 0; c < (S_ * 64 + 255) / 256; ++c) {
        int idx = c * 256 + tid;
        int j = idx >> 6, d = idx & 63;
        bool valid = (j < S_);
        float val = 0.f;
        if (valid) {
            val = fmaxf(kbase[(size_t)j * (3 * E_) + d], 0.f);
            kT[d * KT_P + j] = val;
        }
        float s = val;
#pragma unroll
        for (int m = 1; m < 64; m <<= 1) s += __shfl_xor(s, m, 64);
        if (valid && lane == 0) ksg[(size_t)head * KT_GP + j] = s;
    }
    __syncthreads();
    float* orow = ktg + (size_t)head * 64 * KT_GP;
    for (int idx = tid; idx < 64 * KT_GP; idx += 256) {
        int d = idx / KT_GP, j = idx - d * KT_GP;
        orow[idx] = (j < S_) ? kT[d * KT_P + j] : 0.f;
    }
}

// ---------------- Tversky attention main: one wave per 4 q-rows ----------------
#define RW 4
#define CHUNK (4 * RW)
__global__ __launch_bounds__(256) void tversky_attn_kernel(const float* __restrict__ qkv,
                                                           const float* __restrict__ ktg,
                                                           const float* __restrict__ ksg,
                                                           __hip_bfloat16* __restrict__ o) {
    __shared__ __align__(16) float q_lds[4][RW][64];
    __shared__ __align__(16) float p_lds[4][RW][200];

    const int tid  = threadIdx.x;
    const int wave = tid >> 6;
    const int lane = tid & 63;
    const int ch = blockIdx.x, hh = blockIdx.y, bb = blockIdx.z;
    const int head = bb * NH_ + hh;
    const int i0 = ch * CHUNK + wave * RW;
    if (i0 >= S_) return;

    float qs[RW];
#pragma unroll
    for (int r = 0; r < RW; ++r) {
        int i = i0 + r;
        float qp = 0.f;
        if (i < S_)
            qp = fmaxf(qkv[((size_t)(bb * S_ + i)) * (3 * E_) + hh * DH_ + lane], 0.f);
        float s = qp;
#pragma unroll
        for (int m = 1; m < 64; m <<= 1) s += __shfl_xor(s, m, 64);
        qs[r] = s;
        q_lds[wave][r][lane] = qp;
    }

    const int j0 = lane, j1 = lane + 64, j2 = lane + 128;
    const int j3c = (lane < 5) ? (lane + 192) : 196;

    const float* ksrow = ksg + (size_t)head * KT_GP;
    const float ks0 = ksrow[j0], ks1 = ksrow[j1], ks2 = ksrow[j2], ks3 = ksrow[j3c];

    const float* ktrow = ktg + (size_t)head * 64 * KT_GP;
    float l[4][RW] = {};
#pragma unroll 4
    for (int d4 = 0; d4 < 16; ++d4) {
        float4 qv[RW];
#pragma unroll
        for (int r = 0; r < RW; ++r) qv[r] = *(const float4*)&q_lds[wave][r][d4 * 4];
#pragma unroll
        for (int dd = 0; dd < 4; ++dd) {
            const float* kr = ktrow + (size_t)(d4 * 4 + dd) * KT_GP;
            float k0 = kr[j0], k1 = kr[j1], k2 = kr[j2], k3 = kr[j3c];
#pragma unroll
            for (int r = 0; r < RW; ++r) {
                float q = (dd == 0) ? qv[r].x : (dd == 1) ? qv[r].y : (dd == 2) ? qv[r].z : qv[r].w;
                l[0][r] += fabsf(q - k0);
                l[1][r] += fabsf(q - k1);
                l[2][r] += fabsf(q - k2);
                l[3][r] += fabsf(q - k3);
            }
        }
    }

#pragma unroll
    for (int r = 0; r < RW; ++r) {
        if (i0 + r >= S_) break;
        float s0 = qs[r] + ks0, s1 = qs[r] + ks1, s2 = qs[r] + ks2, s3 = qs[r] + ks3;
        float sc0 = (s0 - l[0][r]) / (s0 + 2e-8f);
        float sc1 = (s1 - l[1][r]) / (s1 + 2e-8f);
        float sc2 = (s2 - l[2][r]) / (s2 + 2e-8f);
        float sc3 = (lane < 5) ? (s3 - l[3][r]) / (s3 + 2e-8f) : -1e30f;
        float vmax = fmaxf(fmaxf(sc0, sc1), fmaxf(sc2, sc3));
#pragma unroll
        for (int m = 1; m < 64; m <<= 1) vmax = fmaxf(vmax, __shfl_xor(vmax, m, 64));
        float e0 = expf(sc0 - vmax);
        float e1 = expf(sc1 - vmax);
        float e2 = expf(sc2 - vmax);
        float e3 = (lane < 5) ? expf(sc3 - vmax) : 0.f;
        float sum = e0 + e1 + e2 + e3;
#pragma unroll
        for (int m = 1; m < 64; m <<= 1) sum += __shfl_xor(sum, m, 64);
        float inv = 1.f / sum;
        p_lds[wave][r][j0] = e0 * inv;
        p_lds[wave][r][j1] = e1 * inv;
        p_lds[wave][r][j2] = e2 * inv;
        if (lane < 5) p_lds[wave][r][lane + 192] = e3 * inv;
    }

    const float* vbase = qkv + (size_t)bb * S_ * (3 * E_) + 2 * E_ + hh * DH_ + lane;
    float acc[RW] = {};
#pragma unroll 4
    for (int j4 = 0; j4 < 196; j4 += 4) {
        float v0 = vbase[(size_t)(j4 + 0) * (3 * E_)];
        float v1 = vbase[(size_t)(j4 + 1) * (3 * E_)];
        float v2 = vbase[(size_t)(j4 + 2) * (3 * E_)];
        float v3 = vbase[(size_t)(j4 + 3) * (3 * E_)];
#pragma unroll
        for (int r = 0; r < RW; ++r) {
            float4 p4 = *(const float4*)&p_lds[wave][r][j4];
            acc[r] += p4.x * v0 + p4.y * v1 + p4.z * v2 + p4.w * v3;
        }
    }
    float v196 = vbase[(size_t)196 * (3 * E_)];
#pragma unroll
    for (int r = 0; r < RW; ++r) {
        int i = i0 + r;
        if (i < S_) {
            float a = acc[r] + p_lds[wave][r][196] * v196;
            o[((size_t)(bb * S_) + i) * E_ + hh * DH_ + lane] = __float2bfloat16(a);
        }
    }
}

// ---------------- head ----------------
__global__ __launch_bounds__(256) void head_kernel(const __hip_bfloat16* __restrict__ ln,
                                                   const float* __restrict__ hw,
                                                   const float* __restrict__ hb,
                                                   float* __restrict__ out) {
    int b = blockIdx.y;
    int n = blockIdx.x * 256 + threadIdx.x;
    __shared__ float xr[E_];
    for (int e = threadIdx.x; e < E_; e += 256)
        xr[e] = __bfloat162float(ln[((size_t)b * S_) * E_ + e]);
    __syncthreads();
    if (n < OUT_) {
        float acc = hb[n];
        for (int e = 0; e < E_; ++e) acc += xr[e] * hw[(size_t)e * OUT_ + n];
        out[(size_t)b * OUT_ + n] = acc;
    }
}

extern "C" void kernel_launch(void* const* d_in, const int* in_sizes, int n_in,
                              void* d_out, int out_size, void* d_ws, size_t ws_size,
                              hipStream_t stream) {
    const float* x        = (const float*)d_in[0];
    const float* conv_w   = (const float*)d_in[1];
    const float* conv_b   = (const float*)d_in[2];
    const float* pos_e    = (const float*)d_in[3];
    const float* cls_t    = (const float*)d_in[4];
    const float* ln1_w    = (const float*)d_in[5];
    const float* ln1_b    = (const float*)d_in[6];
    const float* attn_w   = (const float*)d_in[7];
    const float* attn_b   = (const float*)d_in[8];
    const float* proj_w   = (const float*)d_in[9];
    const float* proj_b   = (const float*)d_in[10];
    const float* ln2_w    = (const float*)d_in[11];
    const float* ln2_b    = (const float*)d_in[12];
    const float* fc1_w    = (const float*)d_in[13];
    const float* fc1_b    = (const float*)d_in[14];
    const float* fc2_w    = (const float*)d_in[15];
    const float* fc2_b    = (const float*)d_in[16];
    const float* lnf_w    = (const float*)d_in[17];
    const float* lnf_b    = (const float*)d_in[18];
    const float* head_w   = (const float*)d_in[19];
    const float* head_b   = (const float*)d_in[20];
    float* out = (float*)d_out;

    // workspace layout
    float* h   = (float*)d_ws;                                    // 605184 f
    float* qkv = h + (size_t)ROWS_ * E_;                          // 1815552 f
    __hip_bfloat16* lnb = (__hip_bfloat16*)(qkv + (size_t)ROWS_ * 3 * E_);
    __hip_bfloat16* ao  = lnb + (size_t)ROWS_ * E_;
    __hip_bfloat16* hid = ao + (size_t)ROWS_ * E_;
    __hip_bfloat16* aim = hid + (size_t)ROWS_ * DFF_;
    __hip_bfloat16* wt  = aim + (size_t)784 * E_;                 // up to 2359296 bf16
    float* ktg  = (float*)(wt + (size_t)2359296);                 // 48*64*200 f
    float* ksg  = ktg + (size_t)48 * 64 * KT_GP;                  // 48*200 f
    float* part = ksg + (size_t)48 * KT_GP;                       // 2*788*768 f

    // ---- patch embed ----
    im2col_kernel<<<(784 * 768) / 256, 256, 0, stream>>>(x, aim);
    cvt_bf16_kernel<<<(768 * 768 + 255) / 256, 256, 0, stream>>>(conv_w, wt, 768 * 768);
    {
        dim3 grid(E_ / 64, (784 + 63) / 64);
        gemm_mfma_kernel<<<grid, 256, 0, stream>>>(aim, wt, conv_b, nullptr, qkv, nullptr,
                                                   nullptr, 784, E_, E_, 0, 1);
    }
    embed_finish_kernel<<<784, 256, 0, stream>>>(qkv, pos_e, h);
    cls_fill_kernel<<<B_, 256, 0, stream>>>(cls_t, h);

    for (int l = 0; l < LL_; ++l) {
        layernorm_kernel<<<ROWS_, 256, 0, stream>>>(h, ln1_w + l * E_, ln1_b + l * E_, lnb);
        {
            dim3 tg((3 * E_) / 32, E_ / 32);
            transpose_bf16_kernel<<<tg, 256, 0, stream>>>(attn_w + (size_t)l * E_ * 3 * E_, wt, E_, 3 * E_);
            dim3 grid((3 * E_) / 64, (ROWS_ + 63) / 64);
            gemm_mfma_kernel<<<grid, 256, 0, stream>>>(lnb, wt, attn_b + (size_t)l * 3 * E_,
                                                       nullptr, qkv, nullptr, nullptr,
                                                       ROWS_, 3 * E_, E_, 0, 1);
        }
        {
            attn_prep_kernel<<<dim3(NH_, B_), 256, 0, stream>>>(qkv, ktg, ksg);
            dim3 grid((S_ + CHUNK - 1) / CHUNK, NH_, B_);
            tversky_attn_kernel<<<grid, 256, 0, stream>>>(qkv, ktg, ksg, ao);
        }
        {
            dim3 tg(E_ / 32, E_ / 32);
            transpose_bf16_kernel<<<tg, 256, 0, stream>>>(proj_w + (size_t)l * E_ * E_, wt, E_, E_);
            dim3 grid(E_ / 64, (ROWS_ + 63) / 64);
            gemm_mfma_kernel<<<grid, 256, 0, stream>>>(ao, wt, proj_b + (size_t)l * E_,
                                                       h, h, nullptr, nullptr,
                                                       ROWS_, E_, E_, 0, 1);
        }
        layernorm_kernel<<<ROWS_, 256, 0, stream>>>(h, ln2_w + l * E_, ln2_b + l * E_, lnb);
        {
            dim3 tg(DFF_ / 32, E_ / 32);
            transpose_bf16_kernel<<<tg, 256, 0, stream>>>(fc1_w + (size_t)l * E_ * DFF_, wt, E_, DFF_);
            dim3 grid(DFF_ / 64, (ROWS_ + 63) / 64);
            gemm_mfma_kernel<<<grid, 256, 0, stream>>>(lnb, wt, fc1_b + (size_t)l * DFF_,
                                                       nullptr, nullptr, hid, nullptr,
                                                       ROWS_, DFF_, E_, 1, 1);
        }
        {
            dim3 tg(E_ / 32, DFF_ / 32);
            transpose_bf16_kernel<<<tg, 256, 0, stream>>>(fc2_w + (size_t)l * DFF_ * E_, wt, DFF_, E_);
            // split-K=2: 12x13x2 = 312 blocks, 24 iters each
            dim3 grid(E_ / 64, (ROWS_ + 63) / 64, 2);
            gemm_mfma_kernel<<<grid, 256, 0, stream>>>(hid, wt, nullptr, nullptr, nullptr, nullptr,
                                                       part, ROWS_, E_, DFF_, 0, 2);
            splitk_reduce_kernel<<<(ROWS_ * E_ + 255) / 256, 256, 0, stream>>>(
                part, fc2_b + (size_t)l * E_, h, h, ROWS_, E_, 2);
        }
    }

    layernorm_kernel<<<ROWS_, 256, 0, stream>>>(h, lnf_w, lnf_b, lnb);
    {
        dim3 grid((OUT_ + 255) / 256, B_);
        head_kernel<<<grid, 256, 0, stream>>>(lnb, head_w, head_b, out);
    }
}

// Round 6
// 455.445 us; speedup vs baseline: 4.5708x; 1.0218x over previous
//
#include <hip/hip_runtime.h>
#include <hip/hip_bf16.h>
#include <math.h>

// Shapes
#define B_  4
#define E_  768
#define NH_ 12
#define DH_ 64
#define LL_ 2
#define DFF_ 3072
#define OUT_ 1000
#define S_  197
#define ROWS_ 788          // B_*S_

typedef __bf16 bf16x8_t __attribute__((ext_vector_type(8)));
typedef float f32x4_t __attribute__((ext_vector_type(4)));

__device__ __forceinline__ float gelu_f(float x) {
    float x3 = x * x * x;
    return 0.5f * x * (1.0f + tanhf(0.7978845608028654f * (x + 0.044715f * x3)));
}

// ---------------- im2col to bf16 ----------------
__global__ __launch_bounds__(256) void im2col_kernel(const float* __restrict__ x,
                                                     __hip_bfloat16* __restrict__ aim) {
    int id = blockIdx.x * 256 + threadIdx.x;        // 784*768 exact
    int row = id / 768, k = id - row * 768;
    int b = row / 196, pr = row - b * 196;
    int hp = pr / 14, wp = pr - hp * 14;
    int c = k >> 8, rem = k & 255, p = rem >> 4, q = rem & 15;
    aim[id] = __float2bfloat16(x[(((size_t)(b * 3 + c) * 224) + hp * 16 + p) * 224 + wp * 16 + q]);
}

// ---------------- mega weight prep: all transposes + conv cvt in ONE dispatch ----------------
// wt arena layout (bf16 elements):
//   conv:   [0, 589824)
//   layer l base = 589824 + l*7077888
//     qkv  +0        (2304x768)
//     proj +1769472  (768x768)
//     fc1  +2359296  (3072x768)
//     fc2  +4718592  (768x3072)
#define WT_CONV   0
#define WT_LBASE  589824
#define WT_LSTRIDE 7077888
#define WT_QKV    0
#define WT_PROJ   1769472
#define WT_FC1    2359296
#define WT_FC2    4718592
// tiles per layer: attn 1728, proj 576, fc1 2304, fc2 2304 -> 6912; 2 layers = 13824
// + conv cvt: 2304 blocks of 256 elems -> grid 16128
__global__ __launch_bounds__(256) void weight_prep_kernel(const float* __restrict__ attn_w,
                                                          const float* __restrict__ proj_w,
                                                          const float* __restrict__ fc1_w,
                                                          const float* __restrict__ fc2_w,
                                                          const float* __restrict__ conv_w,
                                                          __hip_bfloat16* __restrict__ wt) {
    int id = blockIdx.x;
    if (id >= 13824) {               // conv_w flat convert (already [N,K])
        int off = (id - 13824) * 256 + threadIdx.x;
        wt[WT_CONV + off] = __float2bfloat16(conv_w[off]);
        return;
    }
    int l = id / 6912, r = id - l * 6912;
    const float* src;
    __hip_bfloat16* dst;
    int K, N, tile;
    size_t lbase = WT_LBASE + (size_t)l * WT_LSTRIDE;
    if (r < 1728)      { src = attn_w + (size_t)l * E_ * 3 * E_; dst = wt + lbase + WT_QKV;  K = E_;   N = 3 * E_; tile = r; }
    else if (r < 2304) { src = proj_w + (size_t)l * E_ * E_;     dst = wt + lbase + WT_PROJ; K = E_;   N = E_;     tile = r - 1728; }
    else if (r < 4608) { src = fc1_w + (size_t)l * E_ * DFF_;    dst = wt + lbase + WT_FC1;  K = E_;   N = DFF_;   tile = r - 2304; }
    else               { src = fc2_w + (size_t)l * DFF_ * E_;    dst = wt + lbase + WT_FC2;  K = DFF_; N = E_;     tile = r - 4608; }
    int ntn = N / 32;
    int kb = (tile / ntn) * 32, nb = (tile % ntn) * 32;
    __shared__ __hip_bfloat16 t[32][33];
    int tx = threadIdx.x & 31, ty = threadIdx.x >> 5;
#pragma unroll
    for (int rr = 0; rr < 32; rr += 8)
        t[ty + rr][tx] = __float2bfloat16(src[(size_t)(kb + ty + rr) * N + nb + tx]);
    __syncthreads();
#pragma unroll
    for (int rr = 0; rr < 32; rr += 8)
        dst[(size_t)(nb + ty + rr) * K + kb + tx] = t[tx][ty + rr];
}

// ---------------- MFMA GEMM: LDS double-buffer, 1 barrier/iter, prefetch depth 2 ----------------
#define BK 64
#define AP 72
__global__ __launch_bounds__(256) void gemm_mfma_kernel(const __hip_bfloat16* __restrict__ A,
                                                        const __hip_bfloat16* __restrict__ WT,
                                                        const float* __restrict__ bias,
                                                        const float* __restrict__ res,
                                                        float* __restrict__ Cf,
                                                        __hip_bfloat16* __restrict__ Cb,
                                                        float* __restrict__ part,
                                                        int M, int N, int K, int act, int KS) {
    __shared__ __align__(16) ushort Asb[2][64 * AP];
    __shared__ __align__(16) ushort Bsb[2][64 * AP];
    const int tid = threadIdx.x;
    const int wave = tid >> 6, lane = tid & 63;
    const int quad = lane >> 4, l15 = lane & 15;
    const int wm = wave >> 1, wn = wave & 1;
    const int m0 = blockIdx.y * 64, n0 = blockIdx.x * 64;

    const int Kc   = K / KS;
    const int kbeg = blockIdx.z * Kc;
    const int n_it = Kc / BK;

    f32x4_t acc[2][2] = {};

    const int c0r = tid >> 3,         c0o = (tid & 7) * 8;
    const int c1r = (tid + 256) >> 3, c1o = c0o;

    uint4 pa0, pa1, pb0, pb1;
    auto load_tile = [&](int kk) {
        pa0 = make_uint4(0, 0, 0, 0);
        pa1 = pa0;
        int gm = m0 + c0r;
        if (gm < M) pa0 = *(const uint4*)&A[(size_t)gm * K + kk + c0o];
        gm = m0 + c1r;
        if (gm < M) pa1 = *(const uint4*)&A[(size_t)gm * K + kk + c1o];
        pb0 = *(const uint4*)&WT[(size_t)(n0 + c0r) * K + kk + c0o];
        pb1 = *(const uint4*)&WT[(size_t)(n0 + c1r) * K + kk + c1o];
    };
    auto store_tile = [&](int buf) {
        *(uint4*)&Asb[buf][c0r * AP + c0o] = pa0;
        *(uint4*)&Asb[buf][c1r * AP + c1o] = pa1;
        *(uint4*)&Bsb[buf][c0r * AP + c0o] = pb0;
        *(uint4*)&Bsb[buf][c1r * AP + c1o] = pb1;
    };

    // prologue: tile0 -> buf0; tile1 -> regs
    load_tile(kbeg);
    store_tile(0);
    if (n_it > 1) load_tile(kbeg + BK);
    __syncthreads();

    for (int it = 0; it < n_it; ++it) {
        const int cur = it & 1, nxt = cur ^ 1;
        if (it + 1 < n_it) {
            store_tile(nxt);                                   // regs loaded 1 iter ago
            if (it + 2 < n_it) load_tile(kbeg + (it + 2) * BK);// lands by it+2
        }
        const ushort* As = Asb[cur];
        const ushort* Bs = Bsb[cur];
#pragma unroll
        for (int ks = 0; ks < BK; ks += 32) {
            bf16x8_t a0 = *(const bf16x8_t*)&As[(32 * wm + l15) * AP + ks + 8 * quad];
            bf16x8_t a1 = *(const bf16x8_t*)&As[(32 * wm + 16 + l15) * AP + ks + 8 * quad];
            bf16x8_t b0 = *(const bf16x8_t*)&Bs[(32 * wn + l15) * AP + ks + 8 * quad];
            bf16x8_t b1 = *(const bf16x8_t*)&Bs[(32 * wn + 16 + l15) * AP + ks + 8 * quad];
            acc[0][0] = __builtin_amdgcn_mfma_f32_16x16x32_bf16(a0, b0, acc[0][0], 0, 0, 0);
            acc[0][1] = __builtin_amdgcn_mfma_f32_16x16x32_bf16(a0, b1, acc[0][1], 0, 0, 0);
            acc[1][0] = __builtin_amdgcn_mfma_f32_16x16x32_bf16(a1, b0, acc[1][0], 0, 0, 0);
            acc[1][1] = __builtin_amdgcn_mfma_f32_16x16x32_bf16(a1, b1, acc[1][1], 0, 0, 0);
        }
        __syncthreads();
    }

    if (part) {
        float* P = part + (size_t)blockIdx.z * M * N;
#pragma unroll
        for (int mi = 0; mi < 2; ++mi)
#pragma unroll
            for (int ni = 0; ni < 2; ++ni) {
                int gn = n0 + 32 * wn + 16 * ni + l15;
#pragma unroll
                for (int r = 0; r < 4; ++r) {
                    int gm = m0 + 32 * wm + 16 * mi + quad * 4 + r;
                    if (gm < M) P[(size_t)gm * N + gn] = acc[mi][ni][r];
                }
            }
        return;
    }

#pragma unroll
    for (int mi = 0; mi < 2; ++mi)
#pragma unroll
        for (int ni = 0; ni < 2; ++ni) {
            int gn = n0 + 32 * wn + 16 * ni + l15;
#pragma unroll
            for (int r = 0; r < 4; ++r) {
                int gm = m0 + 32 * wm + 16 * mi + quad * 4 + r;
                if (gm < M) {
                    float v = acc[mi][ni][r] + bias[gn];
                    if (act == 1) v = gelu_f(v);
                    if (res) v += res[(size_t)gm * N + gn];
                    if (Cf) Cf[(size_t)gm * N + gn] = v;
                    else    Cb[(size_t)gm * N + gn] = __float2bfloat16(v);
                }
            }
        }
}

// ---------------- split-K reduce + epilogue (fp32 out) ----------------
__global__ __launch_bounds__(256) void splitk_reduce_kernel(const float* __restrict__ part,
                                                            const float* __restrict__ bias,
                                                            const float* __restrict__ res,
                                                            float* __restrict__ Cf,
                                                            int M, int N, int KS) {
    int i = blockIdx.x * 256 + threadIdx.x;
    if (i >= M * N) return;
    int n = i % N;
    float v = bias[n];
    for (int s = 0; s < KS; ++s) v += part[(size_t)s * M * N + i];
    if (res) v += res[i];
    Cf[i] = v;
}

// ---------------- embed finish + cls fill (one dispatch, 788 blocks) ----------------
__global__ __launch_bounds__(256) void embed_cls_kernel(const float* __restrict__ tmp,
                                                        const float* __restrict__ pe,
                                                        const float* __restrict__ ct,
                                                        float* __restrict__ h) {
    int row = blockIdx.x;                 // 0..787 = b*197+s
    int b = row / S_, s = row - b * S_;
    float* hr = h + (size_t)row * E_;
    if (s == 0) {
        for (int e = threadIdx.x; e < E_; e += 256) hr[e] = ct[e];
    } else {
        int pr = s - 1;
        const float* tr = tmp + (size_t)(b * 196 + pr) * E_;
        const float* pr_ = pe + (size_t)pr * E_;
        for (int e = threadIdx.x; e < E_; e += 256) hr[e] = tr[e] + pr_[e];
    }
}

// ---------------- LayerNorm (fp32 in, bf16 out) ----------------
__global__ __launch_bounds__(256) void layernorm_kernel(const float* __restrict__ x,
                                                        const float* __restrict__ w,
                                                        const float* __restrict__ b,
                                                        __hip_bfloat16* __restrict__ y) {
    int row = blockIdx.x;
    const float* xr = x + (size_t)row * E_;
    int tid = threadIdx.x;
    float v0 = xr[tid], v1 = xr[tid + 256], v2 = xr[tid + 512];
    float s  = v0 + v1 + v2;
    float sq = v0 * v0 + v1 * v1 + v2 * v2;
#pragma unroll
    for (int m = 1; m < 64; m <<= 1) {
        s  += __shfl_xor(s, m, 64);
        sq += __shfl_xor(sq, m, 64);
    }
    __shared__ float ss[4], sqs[4];
    int wave = tid >> 6, lane = tid & 63;
    if (lane == 0) { ss[wave] = s; sqs[wave] = sq; }
    __syncthreads();
    s  = ss[0] + ss[1] + ss[2] + ss[3];
    sq = sqs[0] + sqs[1] + sqs[2] + sqs[3];
    float mu   = s * (1.0f / 768.0f);
    float var  = sq * (1.0f / 768.0f) - mu * mu;
    float rstd = rsqrtf(var + 1e-5f);
    __hip_bfloat16* yr = y + (size_t)row * E_;
    yr[tid]       = __float2bfloat16((v0 - mu) * rstd * w[tid]       + b[tid]);
    yr[tid + 256] = __float2bfloat16((v1 - mu) * rstd * w[tid + 256] + b[tid + 256]);
    yr[tid + 512] = __float2bfloat16((v2 - mu) * rstd * w[tid + 512] + b[tid + 512]);
}

// ---------------- attention prep ----------------
#define KT_P 201
#define KT_GP 200
__global__ __launch_bounds__(256) void attn_prep_kernel(const float* __restrict__ qkv,
                                                        float* __restrict__ ktg,
                                                        float* __restrict__ ksg) {
    __shared__ float kT[64 * KT_P];
    const int tid = threadIdx.x;
    const int lane = tid & 63;
    const int hh = blockIdx.x, bb = blockIdx.y;
    const int head = bb * NH_ + hh;
    const float* kbase = qkv + (size_t)bb * S_ * (3 * E_) + E_ + hh * DH_;

    for (int c = 0; c < (S_ * 64 + 255) / 256; ++c) {
        int idx = c * 256 + tid;
        int j = idx >> 6, d = idx & 63;
        bool valid = (j < S_);
        float val = 0.f;
        if (valid) {
            val = fmaxf(kbase[(size_t)j * (3 * E_) + d], 0.f);
            kT[d * KT_P + j] = val;
        }
        float s = val;
#pragma unroll
        for (int m = 1; m < 64; m <<= 1) s += __shfl_xor(s, m, 64);
        if (valid && lane == 0) ksg[(size_t)head * KT_GP + j] = s;
    }
    __syncthreads();
    float* orow = ktg + (size_t)head * 64 * KT_GP;
    for (int idx = tid; idx < 64 * KT_GP; idx += 256) {
        int d = idx / KT_GP, j = idx - d * KT_GP;
        orow[idx] = (j < S_) ? kT[d * KT_P + j] : 0.f;
    }
}

// ---------------- Tversky attention main ----------------
#define RW 4
#define CHUNK (4 * RW)
__global__ __launch_bounds__(256) void tversky_attn_kernel(const float* __restrict__ qkv,
                                                           const float* __restrict__ ktg,
                                                           const float* __restrict__ ksg,
                                                           __hip_bfloat16* __restrict__ o) {
    __shared__ __align__(16) float q_lds[4][RW][64];
    __shared__ __align__(16) float p_lds[4][RW][200];

    const int tid  = threadIdx.x;
    const int wave = tid >> 6;
    const int lane = tid & 63;
    const int ch = blockIdx.x, hh = blockIdx.y, bb = blockIdx.z;
    const int head = bb * NH_ + hh;
    const int i0 = ch * CHUNK + wave * RW;
    if (i0 >= S_) return;

    float qs[RW];
#pragma unroll
    for (int r = 0; r < RW; ++r) {
        int i = i0 + r;
        float qp = 0.f;
        if (i < S_)
            qp = fmaxf(qkv[((size_t)(bb * S_ + i)) * (3 * E_) + hh * DH_ + lane], 0.f);
        float s = qp;
#pragma unroll
        for (int m = 1; m < 64; m <<= 1) s += __shfl_xor(s, m, 64);
        qs[r] = s;
        q_lds[wave][r][lane] = qp;
    }

    const int j0 = lane, j1 = lane + 64, j2 = lane + 128;
    const int j3c = (lane < 5) ? (lane + 192) : 196;

    const float* ksrow = ksg + (size_t)head * KT_GP;
    const float ks0 = ksrow[j0], ks1 = ksrow[j1], ks2 = ksrow[j2], ks3 = ksrow[j3c];

    const float* ktrow = ktg + (size_t)head * 64 * KT_GP;
    float l[4][RW] = {};
#pragma unroll 4
    for (int d4 = 0; d4 < 16; ++d4) {
        float4 qv[RW];
#pragma unroll
        for (int r = 0; r < RW; ++r) qv[r] = *(const float4*)&q_lds[wave][r][d4 * 4];
#pragma unroll
        for (int dd = 0; dd < 4; ++dd) {
            const float* kr = ktrow + (size_t)(d4 * 4 + dd) * KT_GP;
            float k0 = kr[j0], k1 = kr[j1], k2 = kr[j2], k3 = kr[j3c];
#pragma unroll
            for (int r = 0; r < RW; ++r) {
                float q = (dd == 0) ? qv[r].x : (dd == 1) ? qv[r].y : (dd == 2) ? qv[r].z : qv[r].w;
                l[0][r] += fabsf(q - k0);
                l[1][r] += fabsf(q - k1);
                l[2][r] += fabsf(q - k2);
                l[3][r] += fabsf(q - k3);
            }
        }
    }

#pragma unroll
    for (int r = 0; r < RW; ++r) {
        if (i0 + r >= S_) break;
        float s0 = qs[r] + ks0, s1 = qs[r] + ks1, s2 = qs[r] + ks2, s3 = qs[r] + ks3;
        float sc0 = (s0 - l[0][r]) / (s0 + 2e-8f);
        float sc1 = (s1 - l[1][r]) / (s1 + 2e-8f);
        float sc2 = (s2 - l[2][r]) / (s2 + 2e-8f);
        float sc3 = (lane < 5) ? (s3 - l[3][r]) / (s3 + 2e-8f) : -1e30f;
        float vmax = fmaxf(fmaxf(sc0, sc1), fmaxf(sc2, sc3));
#pragma unroll
        for (int m = 1; m < 64; m <<= 1) vmax = fmaxf(vmax, __shfl_xor(vmax, m, 64));
        float e0 = expf(sc0 - vmax);
        float e1 = expf(sc1 - vmax);
        float e2 = expf(sc2 - vmax);
        float e3 = (lane < 5) ? expf(sc3 - vmax) : 0.f;
        float sum = e0 + e1 + e2 + e3;
#pragma unroll
        for (int m = 1; m < 64; m <<= 1) sum += __shfl_xor(sum, m, 64);
        float inv = 1.f / sum;
        p_lds[wave][r][j0] = e0 * inv;
        p_lds[wave][r][j1] = e1 * inv;
        p_lds[wave][r][j2] = e2 * inv;
        if (lane < 5) p_lds[wave][r][lane + 192] = e3 * inv;
    }

    const float* vbase = qkv + (size_t)bb * S_ * (3 * E_) + 2 * E_ + hh * DH_ + lane;
    float acc[RW] = {};
#pragma unroll 4
    for (int j4 = 0; j4 < 196; j4 += 4) {
        float v0 = vbase[(size_t)(j4 + 0) * (3 * E_)];
        float v1 = vbase[(size_t)(j4 + 1) * (3 * E_)];
        float v2 = vbase[(size_t)(j4 + 2) * (3 * E_)];
        float v3 = vbase[(size_t)(j4 + 3) * (3 * E_)];
#pragma unroll
        for (int r = 0; r < RW; ++r) {
            float4 p4 = *(const float4*)&p_lds[wave][r][j4];
            acc[r] += p4.x * v0 + p4.y * v1 + p4.z * v2 + p4.w * v3;
        }
    }
    float v196 = vbase[(size_t)196 * (3 * E_)];
#pragma unroll
    for (int r = 0; r < RW; ++r) {
        int i = i0 + r;
        if (i < S_) {
            float a = acc[r] + p_lds[wave][r][196] * v196;
            o[((size_t)(bb * S_) + i) * E_ + hh * DH_ + lane] = __float2bfloat16(a);
        }
    }
}

// ---------------- head with fused final LN (reads fp32 h, only cls rows) ----------------
__global__ __launch_bounds__(256) void head_ln_kernel(const float* __restrict__ h,
                                                      const float* __restrict__ lw,
                                                      const float* __restrict__ lb,
                                                      const float* __restrict__ hw,
                                                      const float* __restrict__ hb,
                                                      float* __restrict__ out) {
    int b = blockIdx.y;
    int tid = threadIdx.x;
    const float* xr0 = h + (size_t)(b * S_) * E_;
    float v0 = xr0[tid], v1 = xr0[tid + 256], v2 = xr0[tid + 512];
    float s  = v0 + v1 + v2;
    float sq = v0 * v0 + v1 * v1 + v2 * v2;
#pragma unroll
    for (int m = 1; m < 64; m <<= 1) {
        s  += __shfl_xor(s, m, 64);
        sq += __shfl_xor(sq, m, 64);
    }
    __shared__ float ss[4], sqs[4];
    __shared__ float xr[E_];
    int wave = tid >> 6, lane = tid & 63;
    if (lane == 0) { ss[wave] = s; sqs[wave] = sq; }
    __syncthreads();
    s  = ss[0] + ss[1] + ss[2] + ss[3];
    sq = sqs[0] + sqs[1] + sqs[2] + sqs[3];
    float mu   = s * (1.0f / 768.0f);
    float var  = sq * (1.0f / 768.0f) - mu * mu;
    float rstd = rsqrtf(var + 1e-5f);
    xr[tid]       = (v0 - mu) * rstd * lw[tid]       + lb[tid];
    xr[tid + 256] = (v1 - mu) * rstd * lw[tid + 256] + lb[tid + 256];
    xr[tid + 512] = (v2 - mu) * rstd * lw[tid + 512] + lb[tid + 512];
    __syncthreads();
    int n = blockIdx.x * 256 + tid;
    if (n < OUT_) {
        float acc = hb[n];
        for (int e = 0; e < E_; ++e) acc += xr[e] * hw[(size_t)e * OUT_ + n];
        out[(size_t)b * OUT_ + n] = acc;
    }
}

extern "C" void kernel_launch(void* const* d_in, const int* in_sizes, int n_in,
                              void* d_out, int out_size, void* d_ws, size_t ws_size,
                              hipStream_t stream) {
    const float* x        = (const float*)d_in[0];
    const float* conv_w   = (const float*)d_in[1];
    const float* conv_b   = (const float*)d_in[2];
    const float* pos_e    = (const float*)d_in[3];
    const float* cls_t    = (const float*)d_in[4];
    const float* ln1_w    = (const float*)d_in[5];
    const float* ln1_b    = (const float*)d_in[6];
    const float* attn_w   = (const float*)d_in[7];
    const float* attn_b   = (const float*)d_in[8];
    const float* proj_w   = (const float*)d_in[9];
    const float* proj_b   = (const float*)d_in[10];
    const float* ln2_w    = (const float*)d_in[11];
    const float* ln2_b    = (const float*)d_in[12];
    const float* fc1_w    = (const float*)d_in[13];
    const float* fc1_b    = (const float*)d_in[14];
    const float* fc2_w    = (const float*)d_in[15];
    const float* fc2_b    = (const float*)d_in[16];
    const float* lnf_w    = (const float*)d_in[17];
    const float* lnf_b    = (const float*)d_in[18];
    const float* head_w   = (const float*)d_in[19];
    const float* head_b   = (const float*)d_in[20];
    float* out = (float*)d_out;

    // workspace layout
    float* h   = (float*)d_ws;                                    // 605184 f
    float* qkv = h + (size_t)ROWS_ * E_;                          // 1815552 f (also patch tmp)
    __hip_bfloat16* lnb = (__hip_bfloat16*)(qkv + (size_t)ROWS_ * 3 * E_);
    __hip_bfloat16* ao  = lnb + (size_t)ROWS_ * E_;
    __hip_bfloat16* hid = ao + (size_t)ROWS_ * E_;
    __hip_bfloat16* aim = hid + (size_t)ROWS_ * DFF_;
    __hip_bfloat16* wt  = aim + (size_t)784 * E_;                 // 14745600 bf16 arena
    float* ktg  = (float*)(wt + (size_t)14745600);                // 48*64*200 f
    float* ksg  = ktg + (size_t)48 * 64 * KT_GP;                  // 48*200 f
    float* part = ksg + (size_t)48 * KT_GP;                       // 2*788*768 f

    // ---- prologue: im2col + all weight prep (1 dispatch) + patch gemm + embed/cls ----
    im2col_kernel<<<(784 * 768) / 256, 256, 0, stream>>>(x, aim);
    weight_prep_kernel<<<16128, 256, 0, stream>>>(attn_w, proj_w, fc1_w, fc2_w, conv_w, wt);
    {
        dim3 grid(E_ / 64, (784 + 63) / 64);
        gemm_mfma_kernel<<<grid, 256, 0, stream>>>(aim, wt + WT_CONV, conv_b, nullptr, qkv, nullptr,
                                                   nullptr, 784, E_, E_, 0, 1);
    }
    embed_cls_kernel<<<ROWS_, 256, 0, stream>>>(qkv, pos_e, cls_t, h);

    for (int l = 0; l < LL_; ++l) {
        const __hip_bfloat16* wl = wt + WT_LBASE + (size_t)l * WT_LSTRIDE;
        layernorm_kernel<<<ROWS_, 256, 0, stream>>>(h, ln1_w + l * E_, ln1_b + l * E_, lnb);
        {
            dim3 grid((3 * E_) / 64, (ROWS_ + 63) / 64);
            gemm_mfma_kernel<<<grid, 256, 0, stream>>>(lnb, wl + WT_QKV, attn_b + (size_t)l * 3 * E_,
                                                       nullptr, qkv, nullptr, nullptr,
                                                       ROWS_, 3 * E_, E_, 0, 1);
        }
        {
            attn_prep_kernel<<<dim3(NH_, B_), 256, 0, stream>>>(qkv, ktg, ksg);
            dim3 grid((S_ + CHUNK - 1) / CHUNK, NH_, B_);
            tversky_attn_kernel<<<grid, 256, 0, stream>>>(qkv, ktg, ksg, ao);
        }
        {
            dim3 grid(E_ / 64, (ROWS_ + 63) / 64);
            gemm_mfma_kernel<<<grid, 256, 0, stream>>>(ao, wl + WT_PROJ, proj_b + (size_t)l * E_,
                                                       h, h, nullptr, nullptr,
                                                       ROWS_, E_, E_, 0, 1);
        }
        layernorm_kernel<<<ROWS_, 256, 0, stream>>>(h, ln2_w + l * E_, ln2_b + l * E_, lnb);
        {
            dim3 grid(DFF_ / 64, (ROWS_ + 63) / 64);
            gemm_mfma_kernel<<<grid, 256, 0, stream>>>(lnb, wl + WT_FC1, fc1_b + (size_t)l * DFF_,
                                                       nullptr, nullptr, hid, nullptr,
                                                       ROWS_, DFF_, E_, 1, 1);
        }
        {
            dim3 grid(E_ / 64, (ROWS_ + 63) / 64, 2);
            gemm_mfma_kernel<<<grid, 256, 0, stream>>>(hid, wl + WT_FC2, nullptr, nullptr, nullptr,
                                                       nullptr, part, ROWS_, E_, DFF_, 0, 2);
            splitk_reduce_kernel<<<(ROWS_ * E_ + 255) / 256, 256, 0, stream>>>(
                part, fc2_b + (size_t)l * E_, h, h, ROWS_, E_, 2);
        }
    }

    {
        dim3 grid((OUT_ + 255) / 256, B_);
        head_ln_kernel<<<grid, 256, 0, stream>>>(h, lnf_w, lnf_b, head_w, head_b, out);
    }
}